// Round 9
// baseline (371.370 us; speedup 1.0000x reference)
//
#include <hip/hip_runtime.h>
#include <hip/hip_bf16.h>
#include <hip/hip_fp16.h>
#include <math.h>

typedef __hip_bfloat16 bf;
typedef float f2 __attribute__((ext_vector_type(2)));

#define BB   16     // batch
#define CC   128    // channels
#define LL   4096   // H*W
#define DM   32     // d_model per chunk
#define DI   64     // d_inner
#define DSN  16     // d_state
#define GG   64     // 4 * BB sequences
#define NC   128    // scan chunks (CL=32)
#define CL   32     // LL / NC
#define TLV  61     // valid output columns per k1 tile (64 loaded, 3 head)
#define NT   68     // ceil(LL / TLV)
#define XS   133    // k1 xnT row stride in dwords (odd -> conflict-free)
#define YS   35     // k1 xiS row stride in dwords
#define XROW 20     // xdbl row stride in dwords (80 B: dw0=dt01, dw1-3 pad, dw4-11=B, dw12-19=C)

__device__ __forceinline__ float bf2f(bf x) { return __bfloat162float(x); }
__device__ __forceinline__ bf f2bf(float x) { return __float2bfloat16(x); }
__device__ __forceinline__ float blo(unsigned v) { return __uint_as_float(v << 16); }
__device__ __forceinline__ float bhi(unsigned v) { return __uint_as_float(v & 0xffff0000u); }
__device__ __forceinline__ float us2f(unsigned short v) { return __uint_as_float((unsigned)v << 16); }
__device__ __forceinline__ unsigned pack2(float a, float b) {
  bf ba = f2bf(a), bb = f2bf(b);
  unsigned short ua = *(unsigned short*)&ba, ub = *(unsigned short*)&bb;
  return (unsigned)ua | ((unsigned)ub << 16);
}

#if __has_builtin(__builtin_amdgcn_exp2f)
#define EXP2F(x) __builtin_amdgcn_exp2f(x)
#else
#define EXP2F(x) exp2f(x)
#endif

__device__ __forceinline__ float sigmoidf_(float x) { return 1.0f / (1.0f + __expf(-x)); }
// fast softplus: max(x,0) + ln2 * log2(1 + exp2(-|x|*log2e))
__device__ __forceinline__ float softplus_fast(float x) {
  float t = EXP2F(-fabsf(x) * 1.44269504088896f);
  return fmaxf(x, 0.0f) + 0.69314718056f * __log2f(1.0f + t);
}

// ---------------- K1: layernorm + in_proj(xi) + causal conv + silu -> u (bf16), xn (bf16) ----------------
// (unchanged)
__global__ __launch_bounds__(256, 4) void k1_ln_conv(
    const float* __restrict__ input, const float* __restrict__ ln_g, const float* __restrict__ ln_b,
    const float* __restrict__ in_proj_w, const float* __restrict__ conv_w, const float* __restrict__ conv_b,
    bf* __restrict__ u_ws, bf* __restrict__ xn_ws) {
  __shared__ unsigned ldsbuf[8960];               // union: xnT fp32 64x133dw / xiS bf16 256x35dw
  __shared__ float mu_s[64], rs_s[64];
  float* xnT = (float*)ldsbuf;
  unsigned short* xiS = (unsigned short*)ldsbuf;
  int b = blockIdx.x / NT;
  int tile = blockIdx.x - b * NT;
  int l0 = tile * TLV;
  int tid = threadIdx.x;
  const float* inb = input + (size_t)b * CC * LL;
#pragma unroll
  for (int k = 0; k < 32; k++) {
    int i = tid + k * 256;
    int j = i & 63, c = i >> 6;
    int l = l0 - 3 + j;
    xnT[j * XS + c] = (l >= 0 && l < LL) ? inb[c * LL + l] : 0.0f;
  }
  __syncthreads();
  if (tid < 64) {
    float s = 0.f, s2 = 0.f;
    for (int c = 0; c < CC; c++) { float v = xnT[tid * XS + c]; s += v; s2 = fmaf(v, v, s2); }
    float mu = s * (1.0f / CC);
    float var = s2 * (1.0f / CC) - mu * mu;
    mu_s[tid] = mu;
    rs_s[tid] = rsqrtf(var + 1e-5f);
  }
  __syncthreads();
#pragma unroll
  for (int k = 0; k < 32; k++) {
    int i = tid + k * 256;
    int j = i & 63, c = i >> 6;
    xnT[j * XS + c] = (xnT[j * XS + c] - mu_s[j]) * rs_s[j] * ln_g[c] + ln_b[c];
  }
  __syncthreads();
  for (int i = tid; i < CC * TLV; i += 256) {
    int c = i / TLV, j2 = i - c * TLV;
    int l = l0 + j2;
    if (l < LL) xn_ws[((size_t)(b * CC + c)) * LL + l] = f2bf(xnT[(j2 + 3) * XS + c]);
  }
  int g = tid >> 6, j = tid & 63;
  float xr[32];
#pragma unroll
  for (int r = 0; r < 32; r++) xr[r] = xnT[j * XS + g * DM + r];
  bool zero_col = (l0 - 3 + j < 0);
  __syncthreads();
#pragma unroll
  for (int c2 = 0; c2 < 4; c2++) {
    float acc[16];
#pragma unroll
    for (int dd = 0; dd < 16; dd++) {
      const float* w = in_proj_w + (c2 * 16 + dd) * DM;
      float a = 0.f;
#pragma unroll
      for (int r = 0; r < 32; r++) a = fmaf(xr[r], w[r], a);
      acc[dd] = zero_col ? 0.f : a;
    }
    unsigned* xo = (unsigned*)&ldsbuf[(g * 64 + j) * YS + c2 * 8];
#pragma unroll
    for (int k = 0; k < 8; k++)
      xo[k] = pack2(acc[2 * k], acc[2 * k + 1]);
  }
  __syncthreads();
  int d = j;
  float cw0 = conv_w[d * 4 + 0], cw1 = conv_w[d * 4 + 1];
  float cw2 = conv_w[d * 4 + 2], cw3 = conv_w[d * 4 + 3];
  float cb = conv_b[d];
  bf* uo = u_ws + (size_t)(g * BB + b) * LL * DI + d;
  float x3 = 0.f, x2 = 0.f, x1 = 0.f, x0 = 0.f;
  for (int jj = 0; jj < 64; jj++) {
    float xi = us2f(xiS[(g * 64 + jj) * (2 * YS) + d]);
    x3 = x2; x2 = x1; x1 = x0; x0 = xi;
    int l = l0 + jj - 3;
    if (jj >= 3 && l < LL) {
      float pre = x3 * cw0 + x2 * cw1 + x1 * cw2 + x0 * cw3 + cb;
      float uu = pre * sigmoidf_(pre);
      uo[(size_t)l * DI] = f2bf(uu);
    }
  }
}

// ---------------- K2: x_proj only -> xdbl rows (dt0,dt1,B,C packed bf16, 80 B/pos) ----------------
// (unchanged)
__global__ __launch_bounds__(256) void k2_xproj(
    const bf* __restrict__ u_ws, const float* __restrict__ x_proj_w,
    unsigned* __restrict__ xdbl) {
  __shared__ unsigned uS[256 * 33];
  int tid = threadIdx.x;
  size_t pos0 = (size_t)blockIdx.x * 256;
  const unsigned* src = (const unsigned*)u_ws + pos0 * 32;
#pragma unroll
  for (int k = 0; k < 32; k++) {
    int idx = tid + k * 256;
    uS[(idx >> 5) * 33 + (idx & 31)] = src[idx];
  }
  __syncthreads();
  float xdb[34];
#pragma unroll
  for (int e = 0; e < 34; e++) xdb[e] = 0.f;
#pragma unroll
  for (int c2 = 0; c2 < 4; c2++) {
    float f[16];
#pragma unroll
    for (int k = 0; k < 8; k++) {
      unsigned v = uS[tid * 33 + c2 * 8 + k];
      f[2 * k] = blo(v); f[2 * k + 1] = bhi(v);
    }
#pragma unroll
    for (int e = 0; e < 34; e++) {
      const float* w = x_proj_w + e * DI + c2 * 16;
      float a = xdb[e];
#pragma unroll
      for (int i = 0; i < 16; i++) a = fmaf(f[i], w[i], a);
      xdb[e] = a;
    }
  }
  unsigned* row = &uS[tid * 33];
  row[0] = pack2(xdb[0], xdb[1]);
#pragma unroll
  for (int n = 0; n < 8; n++) row[4 + n]  = pack2(xdb[2 + 2 * n], xdb[3 + 2 * n]);
#pragma unroll
  for (int n = 0; n < 8; n++) row[12 + n] = pack2(xdb[18 + 2 * n], xdb[19 + 2 * n]);
  __syncthreads();
  unsigned* dst = xdbl + pos0 * XROW;
#pragma unroll
  for (int k = 0; k < XROW; k++) {
    int idx = tid + k * 256;
    int r = idx / XROW, c = idx - r * XROW;
    dst[idx] = uS[r * 33 + c];
  }
}

// A2[n] == (n+1)*A2[0] for this problem's A = arange(1..16); guarded fast path.
__device__ __forceinline__ bool ladder_check(const float* A_log, int d, float a0) {
  bool ok = true;
#pragma unroll
  for (int n = 1; n < DSN; n++) {
    float an = -__expf(A_log[d * DSN + n]) * 1.44269504088896f;
    ok = ok && (fabsf(an / a0 - (float)(n + 1)) < 1e-3f);
  }
  return ok;
}

// ---------------- K3: scan pass A — local states + chunk delta-sums ----------------
// Round-9: xdbl LDS staging (proven in k56: kills the per-step s_load L2-miss stall)
// + packed-f32 inner loop (v_pk_fma_f32 via float2, halves inner-loop VALU issues).
__global__ __launch_bounds__(256, 8) void k3_scanA(
    const unsigned* __restrict__ xdbl, const bf* __restrict__ u_ws,
    const float* __restrict__ A_log, const float* __restrict__ dt_proj_w,
    const float* __restrict__ dt_proj_b,
    __half* __restrict__ hloc, __half* __restrict__ ssum_ws) {
  __shared__ __align__(16) unsigned bS3[4 * 256];  // per-wave 32 rows x 8 dw (B)
  __shared__ unsigned dtS3[4 * 32];                // per-wave 32 rows dt
  int tid = threadIdx.x;
  int wv = __builtin_amdgcn_readfirstlane(tid >> 6);            // wave in block 0..3
  int wid = __builtin_amdgcn_readfirstlane(blockIdx.x * 4 + wv); // linear (s,chunk)
  int s = wid >> 7, chunk = wid & (NC - 1);
  int d = tid & 63;
  float a0 = -__expf(A_log[d * DSN]) * 1.44269504088896f;
  bool ok = ladder_check(A_log, d, a0);
  float w0 = dt_proj_w[2 * d], w1 = dt_proj_w[2 * d + 1], bd = dt_proj_b[d];
  f2 h2[8];
#pragma unroll
  for (int p2 = 0; p2 < 8; p2++) { h2[p2].x = 0.f; h2[p2].y = 0.f; }
  float ss = 0.f;
  size_t base = (size_t)s * LL + (size_t)chunk * CL;
  const unsigned short* up = (const unsigned short*)u_ws + base * DI + d;
  const unsigned* xrow = xdbl + base * XROW;
  // ---- wave-private staging: 32 rows of (dt, B) -> LDS (no barrier needed) ----
  int wb = wv * 256, wd3 = wv * 32;
#pragma unroll
  for (int k = 0; k < 4; k++) {
    int jj2 = k * 64 + d;                          // 0..255
    bS3[wb + jj2] = xrow[(jj2 >> 3) * XROW + 4 + (jj2 & 7)];
  }
  if (d < 32) dtS3[wd3 + d] = xrow[d * XROW];
  if (ok) {
    for (int t = 0; t < CL; t++) {
      unsigned dtp = dtS3[wd3 + t];
      uint4 bA = *(const uint4*)&bS3[wb + t * 8];
      uint4 bB = *(const uint4*)&bS3[wb + t * 8 + 4];
      float x = fmaf(bhi(dtp), w1, fmaf(blo(dtp), w0, bd));
      float delta = softplus_fast(x);
      float uu = us2f(up[(size_t)t * DI]);
      float du = delta * uu;
      ss += delta;
      float E = EXP2F(delta * a0);
      float E2 = E * E;
      f2 e2; e2.x = E; e2.y = E2;
      f2 E22; E22.x = E2; E22.y = E2;
      f2 du2; du2.x = du; du2.y = du;
      unsigned bw[8] = {bA.x, bA.y, bA.z, bA.w, bB.x, bB.y, bB.z, bB.w};
#pragma unroll
      for (int p2 = 0; p2 < 8; p2++) {
        f2 Bp; Bp.x = blo(bw[p2]); Bp.y = bhi(bw[p2]);
        h2[p2] = h2[p2] * e2 + Bp * du2;           // v_pk_fma_f32
        e2 = e2 * E22;                             // v_pk_mul_f32
      }
    }
  } else {
    f2 A2p[8];
#pragma unroll
    for (int p2 = 0; p2 < 8; p2++) {
      A2p[p2].x = -__expf(A_log[d * DSN + 2 * p2]) * 1.44269504088896f;
      A2p[p2].y = -__expf(A_log[d * DSN + 2 * p2 + 1]) * 1.44269504088896f;
    }
    for (int t = 0; t < CL; t++) {
      unsigned dtp = dtS3[wd3 + t];
      uint4 bA = *(const uint4*)&bS3[wb + t * 8];
      uint4 bB = *(const uint4*)&bS3[wb + t * 8 + 4];
      float x = fmaf(bhi(dtp), w1, fmaf(blo(dtp), w0, bd));
      float delta = softplus_fast(x);
      float uu = us2f(up[(size_t)t * DI]);
      float du = delta * uu;
      ss += delta;
      f2 du2; du2.x = du; du2.y = du;
      unsigned bw[8] = {bA.x, bA.y, bA.z, bA.w, bB.x, bB.y, bB.z, bB.w};
#pragma unroll
      for (int p2 = 0; p2 < 8; p2++) {
        f2 ee; ee.x = EXP2F(delta * A2p[p2].x); ee.y = EXP2F(delta * A2p[p2].y);
        f2 Bp; Bp.x = blo(bw[p2]); Bp.y = bhi(bw[p2]);
        h2[p2] = h2[p2] * ee + Bp * du2;
      }
    }
  }
  size_t ob = (size_t)wid * (DSN * DI) + d;
#pragma unroll
  for (int n = 0; n < DSN; n++)
    hloc[ob + n * DI] = __float2half((n & 1) ? h2[n >> 1].y : h2[n >> 1].x);
  ssum_ws[wid * DI + d] = __float2half(ss);
}

// ---------------- K4: cross-chunk combine ----------------
// (unchanged from round 4)
__global__ __launch_bounds__(1024) void k4_combine(
    const __half* __restrict__ ssum_ws, const float* __restrict__ A_log, __half* hloc_hin) {
  int s = blockIdx.x;
  int tid = threadIdx.x;
  int n = tid >> 6, d = tid & 63;
  float A2 = -__expf(A_log[d * DSN + n]) * 1.44269504088896f;
  float h = 0.f;
  for (int k = 0; k < NC; k++) {
    size_t idx = (size_t)(s * NC + k) * (DSN * DI) + n * DI + d;
    float ss = __half2float(ssum_ws[(s * NC + k) * DI + d]);
    float ap = EXP2F(A2 * ss);
    float hl = __half2float(hloc_hin[idx]);
    hloc_hin[idx] = __float2half(h);
    h = fmaf(h, ap, hl);
  }
}

// ---------------- K56: scan pass C (y2 -> LDS) + z-gate + out_proj + residual -> output (fp32) ----------------
// Round-9 (on the round-8 structure, which converted the s_load stall into VALU-busy):
//  * compact xdbl stage: dtS (1 dw/row) + bcS (16 dw/row, 16B-aligned) -> LDS
//    54272 -> 51200 B (back under the 3-blocks/CU line).
//  * packed-f32 inner loop: float2 h2/e2, mul+add contraction -> v_pk_fma_f32 /
//    v_pk_mul_f32; inner-loop VALU issues 64 -> 32 per step (VALUBusy measured 77%
//    -> issue-bound; fewer issues is the lever now).
//  Epilogue (z-proj after barrier + balanced out_proj) unchanged from round 8.
__global__ __launch_bounds__(512, 4) void k56_scan_final(
    const unsigned* __restrict__ xdbl, const bf* __restrict__ u_ws,
    const float* __restrict__ A_log, const float* __restrict__ dt_proj_w,
    const float* __restrict__ dt_proj_b, const float* __restrict__ Dw,
    const __half* __restrict__ hin, const bf* __restrict__ xn_ws,
    const float* __restrict__ in_proj_w, const float* __restrict__ out_proj_w,
    float* __restrict__ out) {
  __shared__ unsigned y2S[4 * 64 * 33];            // 33792 B: per-g 64 rows x 33 dw
  __shared__ __align__(16) unsigned bcS[8 * 512];  // 16384 B: per-wave 32 rows x 16 dw (B,C)
  __shared__ unsigned dtS[8 * 32];                 // 1024 B: per-wave 32 rows dt
  int b = blockIdx.x >> 6;
  int cpair = blockIdx.x & 63;                     // 64 col-tiles of 64
  int l0b = cpair * 64;                            // block's first output column
  int tid = threadIdx.x;
  int w = __builtin_amdgcn_readfirstlane(tid >> 6); // 0..7
  int g = w >> 1, half = w & 1;
  int d = tid & 63;
  int chunk = cpair * 2 + half;                    // scalar
  int s_u = __builtin_amdgcn_readfirstlane(g * BB + b);
  float a0 = -__expf(A_log[d * DSN]) * 1.44269504088896f;
  bool ok = ladder_check(A_log, d, a0);
  float w0 = dt_proj_w[2 * d], w1 = dt_proj_w[2 * d + 1], bd = dt_proj_b[d];
  float Dd = Dw[d];
  size_t hb = (size_t)(s_u * NC + chunk) * (DSN * DI) + d;
  f2 h2[8];
#pragma unroll
  for (int p2 = 0; p2 < 8; p2++) {
    h2[p2].x = __half2float(hin[hb + (2 * p2) * DI]);
    h2[p2].y = __half2float(hin[hb + (2 * p2 + 1) * DI]);
  }
  size_t base = (size_t)s_u * LL + (size_t)chunk * CL;
  const unsigned short* up = (const unsigned short*)u_ws + base * DI + d;
  const unsigned* xrow = xdbl + base * XROW;
  // ---- wave-private staging: 32 rows of (dt, B, C) -> LDS (no barrier needed) ----
  int wbc = w * 512, wdt = w * 32;
#pragma unroll
  for (int k = 0; k < 8; k++) {
    int jj2 = k * 64 + d;                          // 0..511
    bcS[wbc + jj2] = xrow[(jj2 >> 4) * XROW + 4 + (jj2 & 15)];
  }
  if (d < 32) dtS[wdt + d] = xrow[d * XROW];
  unsigned short* yout = (unsigned short*)y2S + g * 4224 + (half * CL) * 66 + d;
  if (ok) {
    for (int t = 0; t < CL; t++) {
      unsigned dtp = dtS[wdt + t];
      uint4 bA = *(const uint4*)&bcS[wbc + t * 16];
      uint4 bB = *(const uint4*)&bcS[wbc + t * 16 + 4];
      uint4 cA = *(const uint4*)&bcS[wbc + t * 16 + 8];
      uint4 cB = *(const uint4*)&bcS[wbc + t * 16 + 12];
      float x = fmaf(bhi(dtp), w1, fmaf(blo(dtp), w0, bd));
      float delta = softplus_fast(x);
      float uu = us2f(up[(size_t)t * DI]);
      float du = delta * uu;
      float E = EXP2F(delta * a0);
      float E2 = E * E;
      f2 e2; e2.x = E; e2.y = E2;
      f2 E22; E22.x = E2; E22.y = E2;
      f2 du2; du2.x = du; du2.y = du;
      f2 y2; y2.x = 0.f; y2.y = 0.f;
      unsigned bw[8] = {bA.x, bA.y, bA.z, bA.w, bB.x, bB.y, bB.z, bB.w};
      unsigned cw[8] = {cA.x, cA.y, cA.z, cA.w, cB.x, cB.y, cB.z, cB.w};
#pragma unroll
      for (int p2 = 0; p2 < 8; p2++) {
        f2 Bp; Bp.x = blo(bw[p2]); Bp.y = bhi(bw[p2]);
        f2 Cp; Cp.x = blo(cw[p2]); Cp.y = bhi(cw[p2]);
        h2[p2] = h2[p2] * e2 + Bp * du2;           // v_pk_fma_f32
        y2 = h2[p2] * Cp + y2;                     // v_pk_fma_f32
        e2 = e2 * E22;                             // v_pk_mul_f32
      }
      float y = y2.x + y2.y;
      bf rv = f2bf(y + uu * Dd);
      yout[t * 66] = *(unsigned short*)&rv;
    }
  } else {
    f2 A2p[8];
#pragma unroll
    for (int p2 = 0; p2 < 8; p2++) {
      A2p[p2].x = -__expf(A_log[d * DSN + 2 * p2]) * 1.44269504088896f;
      A2p[p2].y = -__expf(A_log[d * DSN + 2 * p2 + 1]) * 1.44269504088896f;
    }
    for (int t = 0; t < CL; t++) {
      unsigned dtp = dtS[wdt + t];
      uint4 bA = *(const uint4*)&bcS[wbc + t * 16];
      uint4 bB = *(const uint4*)&bcS[wbc + t * 16 + 4];
      uint4 cA = *(const uint4*)&bcS[wbc + t * 16 + 8];
      uint4 cB = *(const uint4*)&bcS[wbc + t * 16 + 12];
      float x = fmaf(bhi(dtp), w1, fmaf(blo(dtp), w0, bd));
      float delta = softplus_fast(x);
      float uu = us2f(up[(size_t)t * DI]);
      float du = delta * uu;
      f2 du2; du2.x = du; du2.y = du;
      f2 y2; y2.x = 0.f; y2.y = 0.f;
      unsigned bw[8] = {bA.x, bA.y, bA.z, bA.w, bB.x, bB.y, bB.z, bB.w};
      unsigned cw[8] = {cA.x, cA.y, cA.z, cA.w, cB.x, cB.y, cB.z, cB.w};
#pragma unroll
      for (int p2 = 0; p2 < 8; p2++) {
        f2 ee; ee.x = EXP2F(delta * A2p[p2].x); ee.y = EXP2F(delta * A2p[p2].y);
        f2 Bp; Bp.x = blo(bw[p2]); Bp.y = bhi(bw[p2]);
        f2 Cp; Cp.x = blo(cw[p2]); Cp.y = bhi(cw[p2]);
        h2[p2] = h2[p2] * ee + Bp * du2;
        y2 = h2[p2] * Cp + y2;
      }
      float y = y2.x + y2.y;
      bf rv = f2bf(y + uu * Dd);
      yout[t * 66] = *(unsigned short*)&rv;
    }
  }
  __syncthreads();
  // ---- z projection (after barrier; acc never lives across the scan) ----
  int p = half;
  int j = d;
  const unsigned short* xnp = (const unsigned short*)xn_ws
                            + ((size_t)(b * CC + g * DM)) * LL + l0b + j;
  float acc[32];                                   // this wave's dd = p*32 .. p*32+31
#pragma unroll
  for (int dd = 0; dd < 32; dd++) acc[dd] = 0.f;
#pragma unroll
  for (int c4 = 0; c4 < 4; c4++) {
    float xc[8];
#pragma unroll
    for (int r8 = 0; r8 < 8; r8++)
      xc[r8] = us2f(xnp[(size_t)(c4 * 8 + r8) * LL]);   // lanes j consecutive -> coalesced
#pragma unroll
    for (int dd = 0; dd < 32; dd++) {              // weights wave-uniform -> s_load
      const float* wz = in_proj_w + (DI + p * 32 + dd) * DM + c4 * 8;
      float a = acc[dd];
#pragma unroll
      for (int r8 = 0; r8 < 8; r8++) a = fmaf(xc[r8], wz[r8], a);
      acc[dd] = a;
    }
  }
  // ---- gate: y3 = y2 * silu(z); own (g,j) row, this wave's dword cols p*16..p*16+15 ----
  const unsigned* yrow = y2S + g * 2112 + j * 33;  // banks (j+k)%32 -> conflict-free
#pragma unroll
  for (int kk = 0; kk < 16; kk++) {
    unsigned v = yrow[p * 16 + kk];
    float z0 = acc[2 * kk], z1 = acc[2 * kk + 1];
    acc[2 * kk]     = blo(v) * (z0 * sigmoidf_(z0));
    acc[2 * kk + 1] = bhi(v) * (z1 * sigmoidf_(z1));
  }
  __syncthreads();                                 // y2S fully consumed -> reuse as partials
  // ---- phase A: partials for the OTHER wave's jj half (both waves work) ----
  float* prow = (float*)y2S + g * 2112 + j * 33;   // stride-33 -> conflict-free
  int jjb = (1 - p) * 16;
#pragma unroll
  for (int jj = 0; jj < 16; jj++) {
    const float* wo = out_proj_w + (jjb + jj) * DI + p * 32;
    float a = 0.f;
#pragma unroll
    for (int dd = 0; dd < 32; dd++) a = fmaf(acc[dd], wo[dd], a);
    prow[jjb + jj] = a;
  }
  __syncthreads();
  // ---- phase B: finalize own half (partial + own dot + residual), store 16 rows/wave ----
  int jf = p * 16;
  float* ob = out + ((size_t)(b * CC + g * DM)) * LL + l0b + j;
#pragma unroll
  for (int jj = 0; jj < 16; jj++) {
    const float* wo = out_proj_w + (jf + jj) * DI + p * 32;
    float a = us2f(xnp[(size_t)(jf + jj) * LL]) + prow[jf + jj];
#pragma unroll
    for (int dd = 0; dd < 32; dd++) a = fmaf(acc[dd], wo[dd], a);
    ob[(size_t)(jf + jj) * LL] = a;                // coalesced 256B
  }
}

extern "C" void kernel_launch(void* const* d_in, const int* in_sizes, int n_in,
                              void* d_out, int out_size, void* d_ws, size_t ws_size,
                              hipStream_t stream) {
  const float* input     = (const float*)d_in[0];
  const float* ln_g      = (const float*)d_in[1];
  const float* ln_b      = (const float*)d_in[2];
  const float* in_proj_w = (const float*)d_in[3];
  const float* conv_w    = (const float*)d_in[4];
  const float* conv_b    = (const float*)d_in[5];
  const float* x_proj_w  = (const float*)d_in[6];
  const float* dt_proj_w = (const float*)d_in[7];
  const float* dt_proj_b = (const float*)d_in[8];
  const float* A_log     = (const float*)d_in[9];
  const float* Dw        = (const float*)d_in[10];
  const float* out_proj_w= (const float*)d_in[11];
  float* out = (float*)d_out;

  char* ws = (char*)d_ws;
  bf*       u_ws  = (bf*)(ws);                    // 32 MiB
  unsigned* xdbl  = (unsigned*)(ws + 33554432);   // 20 MiB
  bf*       xn_ws = (bf*)(ws + 54525952);         // 16 MiB
  __half*   hloc  = (__half*)(ws + 71303168);     // 16 MiB fp16 (NC=128; hin aliases after k4)
  __half*   ssum  = (__half*)(ws + 88080384);     // 1 MiB fp16 (total 89,128,960 B — known-good)
  (void)in_sizes; (void)n_in; (void)out_size; (void)ws_size;

  hipLaunchKernelGGL(k1_ln_conv, dim3(BB * NT), dim3(256), 0, stream,
                     input, ln_g, ln_b, in_proj_w, conv_w, conv_b, u_ws, xn_ws);
  hipLaunchKernelGGL(k2_xproj, dim3(1024), dim3(256), 0, stream,
                     u_ws, x_proj_w, xdbl);
  hipLaunchKernelGGL(k3_scanA, dim3(GG * NC / 4), dim3(256), 0, stream,
                     xdbl, u_ws, A_log, dt_proj_w, dt_proj_b, hloc, ssum);
  hipLaunchKernelGGL(k4_combine, dim3(GG), dim3(1024), 0, stream,
                     ssum, A_log, hloc);
  hipLaunchKernelGGL(k56_scan_final, dim3(BB * NC / 2), dim3(512), 0, stream,
                     xdbl, u_ws, A_log, dt_proj_w, dt_proj_b, Dw, hloc, xn_ws,
                     in_proj_w, out_proj_w, out);
}

// Round 10
// 367.696 us; speedup vs baseline: 1.0100x; 1.0100x over previous
//
#include <hip/hip_runtime.h>
#include <hip/hip_bf16.h>
#include <hip/hip_fp16.h>
#include <math.h>

typedef __hip_bfloat16 bf;
typedef float f2 __attribute__((ext_vector_type(2)));
typedef _Float16 hf2 __attribute__((ext_vector_type(2)));

#define BB   16     // batch
#define CC   128    // channels
#define LL   4096   // H*W
#define DM   32     // d_model per chunk
#define DI   64     // d_inner
#define DSN  16     // d_state
#define GG   64     // 4 * BB sequences
#define NC   128    // scan chunks (CL=32)
#define CL   32     // LL / NC
#define TLV  61     // valid output columns per k1 tile (64 loaded, 3 head)
#define NT   68     // ceil(LL / TLV)
#define XS   133    // k1 xnT row stride in dwords (odd -> conflict-free)
#define YS   35     // k1 xiS row stride in dwords
#define XROW 20     // xdbl row stride in dwords (80 B: dw0=dt01 bf16, dw1-3 pad, dw4-11=B f16, dw12-19=C f16)

__device__ __forceinline__ float bf2f(bf x) { return __bfloat162float(x); }
__device__ __forceinline__ bf f2bf(float x) { return __float2bfloat16(x); }
__device__ __forceinline__ float blo(unsigned v) { return __uint_as_float(v << 16); }
__device__ __forceinline__ float bhi(unsigned v) { return __uint_as_float(v & 0xffff0000u); }
__device__ __forceinline__ float us2f(unsigned short v) { return __uint_as_float((unsigned)v << 16); }
__device__ __forceinline__ unsigned pack2(float a, float b) {
  bf ba = f2bf(a), bb = f2bf(b);
  unsigned short ua = *(unsigned short*)&ba, ub = *(unsigned short*)&bb;
  return (unsigned)ua | ((unsigned)ub << 16);
}
// f16 pair pack (k2 emits B/C as f16 so the scan consumes them with NO unpack)
__device__ __forceinline__ unsigned pack2h(float a, float b) {
  _Float16 ha = (_Float16)a, hb = (_Float16)b;
  unsigned short ua = *(unsigned short*)&ha, ub = *(unsigned short*)&hb;
  return (unsigned)ua | ((unsigned)ub << 16);
}
__device__ __forceinline__ hf2 u2h2(unsigned v) {
  union { unsigned u; hf2 h; } c; c.u = v; return c.h;
}

#if __has_builtin(__builtin_amdgcn_exp2f)
#define EXP2F(x) __builtin_amdgcn_exp2f(x)
#else
#define EXP2F(x) exp2f(x)
#endif

#if __has_builtin(__builtin_amdgcn_fdot2)
#define FDOT2(a, b, c) __builtin_amdgcn_fdot2((a), (b), (c), false)
#else
#define FDOT2(a, b, c) ((c) + (float)(a).x * (float)(b).x + (float)(a).y * (float)(b).y)
#endif

__device__ __forceinline__ float sigmoidf_(float x) { return 1.0f / (1.0f + __expf(-x)); }
// fast softplus: max(x,0) + ln2 * log2(1 + exp2(-|x|*log2e))
__device__ __forceinline__ float softplus_fast(float x) {
  float t = EXP2F(-fabsf(x) * 1.44269504088896f);
  return fmaxf(x, 0.0f) + 0.69314718056f * __log2f(1.0f + t);
}

// ---------------- K1: layernorm + in_proj(xi) + causal conv + silu -> u (bf16), xn (bf16) ----------------
// (unchanged)
__global__ __launch_bounds__(256, 4) void k1_ln_conv(
    const float* __restrict__ input, const float* __restrict__ ln_g, const float* __restrict__ ln_b,
    const float* __restrict__ in_proj_w, const float* __restrict__ conv_w, const float* __restrict__ conv_b,
    bf* __restrict__ u_ws, bf* __restrict__ xn_ws) {
  __shared__ unsigned ldsbuf[8960];               // union: xnT fp32 64x133dw / xiS bf16 256x35dw
  __shared__ float mu_s[64], rs_s[64];
  float* xnT = (float*)ldsbuf;
  unsigned short* xiS = (unsigned short*)ldsbuf;
  int b = blockIdx.x / NT;
  int tile = blockIdx.x - b * NT;
  int l0 = tile * TLV;
  int tid = threadIdx.x;
  const float* inb = input + (size_t)b * CC * LL;
#pragma unroll
  for (int k = 0; k < 32; k++) {
    int i = tid + k * 256;
    int j = i & 63, c = i >> 6;
    int l = l0 - 3 + j;
    xnT[j * XS + c] = (l >= 0 && l < LL) ? inb[c * LL + l] : 0.0f;
  }
  __syncthreads();
  if (tid < 64) {
    float s = 0.f, s2 = 0.f;
    for (int c = 0; c < CC; c++) { float v = xnT[tid * XS + c]; s += v; s2 = fmaf(v, v, s2); }
    float mu = s * (1.0f / CC);
    float var = s2 * (1.0f / CC) - mu * mu;
    mu_s[tid] = mu;
    rs_s[tid] = rsqrtf(var + 1e-5f);
  }
  __syncthreads();
#pragma unroll
  for (int k = 0; k < 32; k++) {
    int i = tid + k * 256;
    int j = i & 63, c = i >> 6;
    xnT[j * XS + c] = (xnT[j * XS + c] - mu_s[j]) * rs_s[j] * ln_g[c] + ln_b[c];
  }
  __syncthreads();
  for (int i = tid; i < CC * TLV; i += 256) {
    int c = i / TLV, j2 = i - c * TLV;
    int l = l0 + j2;
    if (l < LL) xn_ws[((size_t)(b * CC + c)) * LL + l] = f2bf(xnT[(j2 + 3) * XS + c]);
  }
  int g = tid >> 6, j = tid & 63;
  float xr[32];
#pragma unroll
  for (int r = 0; r < 32; r++) xr[r] = xnT[j * XS + g * DM + r];
  bool zero_col = (l0 - 3 + j < 0);
  __syncthreads();
#pragma unroll
  for (int c2 = 0; c2 < 4; c2++) {
    float acc[16];
#pragma unroll
    for (int dd = 0; dd < 16; dd++) {
      const float* w = in_proj_w + (c2 * 16 + dd) * DM;
      float a = 0.f;
#pragma unroll
      for (int r = 0; r < 32; r++) a = fmaf(xr[r], w[r], a);
      acc[dd] = zero_col ? 0.f : a;
    }
    unsigned* xo = (unsigned*)&ldsbuf[(g * 64 + j) * YS + c2 * 8];
#pragma unroll
    for (int k = 0; k < 8; k++)
      xo[k] = pack2(acc[2 * k], acc[2 * k + 1]);
  }
  __syncthreads();
  int d = j;
  float cw0 = conv_w[d * 4 + 0], cw1 = conv_w[d * 4 + 1];
  float cw2 = conv_w[d * 4 + 2], cw3 = conv_w[d * 4 + 3];
  float cb = conv_b[d];
  bf* uo = u_ws + (size_t)(g * BB + b) * LL * DI + d;
  float x3 = 0.f, x2 = 0.f, x1 = 0.f, x0 = 0.f;
  for (int jj = 0; jj < 64; jj++) {
    float xi = us2f(xiS[(g * 64 + jj) * (2 * YS) + d]);
    x3 = x2; x2 = x1; x1 = x0; x0 = xi;
    int l = l0 + jj - 3;
    if (jj >= 3 && l < LL) {
      float pre = x3 * cw0 + x2 * cw1 + x1 * cw2 + x0 * cw3 + cb;
      float uu = pre * sigmoidf_(pre);
      uo[(size_t)l * DI] = f2bf(uu);
    }
  }
}

// ---------------- K2: x_proj only -> xdbl rows (dt bf16; B,C packed f16) ----------------
// f16 B/C: the scan kernels consume the packed dwords directly with v_pk_*_f16 /
// v_dot2_f32_f16 — removes the 32 unpack VALU ops per scan step that round-9 PMC
// showed were the residual issue-bound cost.
__global__ __launch_bounds__(256) void k2_xproj(
    const bf* __restrict__ u_ws, const float* __restrict__ x_proj_w,
    unsigned* __restrict__ xdbl) {
  __shared__ unsigned uS[256 * 33];
  int tid = threadIdx.x;
  size_t pos0 = (size_t)blockIdx.x * 256;
  const unsigned* src = (const unsigned*)u_ws + pos0 * 32;
#pragma unroll
  for (int k = 0; k < 32; k++) {
    int idx = tid + k * 256;
    uS[(idx >> 5) * 33 + (idx & 31)] = src[idx];
  }
  __syncthreads();
  float xdb[34];
#pragma unroll
  for (int e = 0; e < 34; e++) xdb[e] = 0.f;
#pragma unroll
  for (int c2 = 0; c2 < 4; c2++) {
    float f[16];
#pragma unroll
    for (int k = 0; k < 8; k++) {
      unsigned v = uS[tid * 33 + c2 * 8 + k];
      f[2 * k] = blo(v); f[2 * k + 1] = bhi(v);
    }
#pragma unroll
    for (int e = 0; e < 34; e++) {
      const float* w = x_proj_w + e * DI + c2 * 16;
      float a = xdb[e];
#pragma unroll
      for (int i = 0; i < 16; i++) a = fmaf(f[i], w[i], a);
      xdb[e] = a;
    }
  }
  unsigned* row = &uS[tid * 33];
  row[0] = pack2(xdb[0], xdb[1]);
#pragma unroll
  for (int n = 0; n < 8; n++) row[4 + n]  = pack2h(xdb[2 + 2 * n], xdb[3 + 2 * n]);
#pragma unroll
  for (int n = 0; n < 8; n++) row[12 + n] = pack2h(xdb[18 + 2 * n], xdb[19 + 2 * n]);
  __syncthreads();
  unsigned* dst = xdbl + pos0 * XROW;
#pragma unroll
  for (int k = 0; k < XROW; k++) {
    int idx = tid + k * 256;
    int r = idx / XROW, c = idx - r * XROW;
    dst[idx] = uS[r * 33 + c];
  }
}

// A2[n] == (n+1)*A2[0] for this problem's A = arange(1..16); guarded fast path.
__device__ __forceinline__ bool ladder_check(const float* A_log, int d, float a0) {
  bool ok = true;
#pragma unroll
  for (int n = 1; n < DSN; n++) {
    float an = -__expf(A_log[d * DSN + n]) * 1.44269504088896f;
    ok = ok && (fabsf(an / a0 - (float)(n + 1)) < 1e-3f);
  }
  return ok;
}

// ---------------- K3: scan pass A — local states + chunk delta-sums ----------------
// f16-packed scan: h carried as 8x hf2 (v_pk_fma_f16 update, no B unpack);
// hloc stores are raw f16 bit-moves. LDS staging as round 9.
__global__ __launch_bounds__(256, 8) void k3_scanA(
    const unsigned* __restrict__ xdbl, const bf* __restrict__ u_ws,
    const float* __restrict__ A_log, const float* __restrict__ dt_proj_w,
    const float* __restrict__ dt_proj_b,
    __half* __restrict__ hloc, __half* __restrict__ ssum_ws) {
  __shared__ __align__(16) unsigned bS3[4 * 256];  // per-wave 32 rows x 8 dw (B f16)
  __shared__ unsigned dtS3[4 * 32];                // per-wave 32 rows dt
  int tid = threadIdx.x;
  int wv = __builtin_amdgcn_readfirstlane(tid >> 6);            // wave in block 0..3
  int wid = __builtin_amdgcn_readfirstlane(blockIdx.x * 4 + wv); // linear (s,chunk)
  int s = wid >> 7, chunk = wid & (NC - 1);
  int d = tid & 63;
  float a0 = -__expf(A_log[d * DSN]) * 1.44269504088896f;
  bool ok = ladder_check(A_log, d, a0);
  float w0 = dt_proj_w[2 * d], w1 = dt_proj_w[2 * d + 1], bd = dt_proj_b[d];
  hf2 h2[8];
#pragma unroll
  for (int p2 = 0; p2 < 8; p2++) h2[p2] = u2h2(0u);
  float ss = 0.f;
  size_t base = (size_t)s * LL + (size_t)chunk * CL;
  const unsigned short* up = (const unsigned short*)u_ws + base * DI + d;
  const unsigned* xrow = xdbl + base * XROW;
  // ---- wave-private staging: 32 rows of (dt, B) -> LDS (no barrier needed) ----
  int wb = wv * 256, wd3 = wv * 32;
#pragma unroll
  for (int k = 0; k < 4; k++) {
    int jj2 = k * 64 + d;                          // 0..255
    bS3[wb + jj2] = xrow[(jj2 >> 3) * XROW + 4 + (jj2 & 7)];
  }
  if (d < 32) dtS3[wd3 + d] = xrow[d * XROW];
  if (ok) {
    for (int t = 0; t < CL; t++) {
      unsigned dtp = dtS3[wd3 + t];
      uint4 bA = *(const uint4*)&bS3[wb + t * 8];
      uint4 bB = *(const uint4*)&bS3[wb + t * 8 + 4];
      float x = fmaf(bhi(dtp), w1, fmaf(blo(dtp), w0, bd));
      float delta = softplus_fast(x);
      float uu = us2f(up[(size_t)t * DI]);
      float du = delta * uu;
      ss += delta;
      float E = EXP2F(delta * a0);
      float E2 = E * E;
      hf2 e2; e2.x = (_Float16)E; e2.y = (_Float16)E2;
      hf2 E22; E22.x = (_Float16)E2; E22.y = (_Float16)E2;
      _Float16 duh = (_Float16)du;
      hf2 du2; du2.x = duh; du2.y = duh;
      unsigned bw[8] = {bA.x, bA.y, bA.z, bA.w, bB.x, bB.y, bB.z, bB.w};
#pragma unroll
      for (int p2 = 0; p2 < 8; p2++) {
        hf2 Bp = u2h2(bw[p2]);
        h2[p2] = h2[p2] * e2 + Bp * du2;           // v_pk_mul_f16 + v_pk_fma_f16
        e2 = e2 * E22;                             // v_pk_mul_f16
      }
    }
  } else {
    f2 A2p[8];
#pragma unroll
    for (int p2 = 0; p2 < 8; p2++) {
      A2p[p2].x = -__expf(A_log[d * DSN + 2 * p2]) * 1.44269504088896f;
      A2p[p2].y = -__expf(A_log[d * DSN + 2 * p2 + 1]) * 1.44269504088896f;
    }
    for (int t = 0; t < CL; t++) {
      unsigned dtp = dtS3[wd3 + t];
      uint4 bA = *(const uint4*)&bS3[wb + t * 8];
      uint4 bB = *(const uint4*)&bS3[wb + t * 8 + 4];
      float x = fmaf(bhi(dtp), w1, fmaf(blo(dtp), w0, bd));
      float delta = softplus_fast(x);
      float uu = us2f(up[(size_t)t * DI]);
      float du = delta * uu;
      ss += delta;
      _Float16 duh = (_Float16)du;
      hf2 du2; du2.x = duh; du2.y = duh;
      unsigned bw[8] = {bA.x, bA.y, bA.z, bA.w, bB.x, bB.y, bB.z, bB.w};
#pragma unroll
      for (int p2 = 0; p2 < 8; p2++) {
        hf2 ee; ee.x = (_Float16)EXP2F(delta * A2p[p2].x); ee.y = (_Float16)EXP2F(delta * A2p[p2].y);
        hf2 Bp = u2h2(bw[p2]);
        h2[p2] = h2[p2] * ee + Bp * du2;
      }
    }
  }
  size_t ob = (size_t)wid * (DSN * DI) + d;
  unsigned short* hl = (unsigned short*)hloc;
#pragma unroll
  for (int n = 0; n < DSN; n++) {
    _Float16 v = (n & 1) ? h2[n >> 1].y : h2[n >> 1].x;
    hl[ob + n * DI] = *(unsigned short*)&v;        // raw f16 bits (hloc is fp16)
  }
  ssum_ws[wid * DI + d] = __float2half(ss);
}

// ---------------- K4: cross-chunk combine ----------------
// (unchanged from round 4)
__global__ __launch_bounds__(1024) void k4_combine(
    const __half* __restrict__ ssum_ws, const float* __restrict__ A_log, __half* hloc_hin) {
  int s = blockIdx.x;
  int tid = threadIdx.x;
  int n = tid >> 6, d = tid & 63;
  float A2 = -__expf(A_log[d * DSN + n]) * 1.44269504088896f;
  float h = 0.f;
  for (int k = 0; k < NC; k++) {
    size_t idx = (size_t)(s * NC + k) * (DSN * DI) + n * DI + d;
    float ss = __half2float(ssum_ws[(s * NC + k) * DI + d]);
    float ap = EXP2F(A2 * ss);
    float hl = __half2float(hloc_hin[idx]);
    hloc_hin[idx] = __float2half(h);
    h = fmaf(h, ap, hl);
  }
}

// ---------------- K56: scan pass C (y2 -> LDS) + z-gate + out_proj + residual -> output (fp32) ----------------
// Round-10: f16-packed scan. B/C consumed as packed f16 (zero unpack); h carried as
// 8x hf2 (pk_fma_f16); y accumulated in f32 via v_dot2_f32_f16 (one issue per pair).
// Inner loop ~8 -> ~4 issues per state-pair. h-init from fp16 hin = raw bit-moves.
// Staging + epilogue unchanged from round 9.
__global__ __launch_bounds__(512, 4) void k56_scan_final(
    const unsigned* __restrict__ xdbl, const bf* __restrict__ u_ws,
    const float* __restrict__ A_log, const float* __restrict__ dt_proj_w,
    const float* __restrict__ dt_proj_b, const float* __restrict__ Dw,
    const __half* __restrict__ hin, const bf* __restrict__ xn_ws,
    const float* __restrict__ in_proj_w, const float* __restrict__ out_proj_w,
    float* __restrict__ out) {
  __shared__ unsigned y2S[4 * 64 * 33];            // 33792 B: per-g 64 rows x 33 dw
  __shared__ __align__(16) unsigned bcS[8 * 512];  // 16384 B: per-wave 32 rows x 16 dw (B,C f16)
  __shared__ unsigned dtS[8 * 32];                 // 1024 B: per-wave 32 rows dt
  int b = blockIdx.x >> 6;
  int cpair = blockIdx.x & 63;                     // 64 col-tiles of 64
  int l0b = cpair * 64;                            // block's first output column
  int tid = threadIdx.x;
  int w = __builtin_amdgcn_readfirstlane(tid >> 6); // 0..7
  int g = w >> 1, half = w & 1;
  int d = tid & 63;
  int chunk = cpair * 2 + half;                    // scalar
  int s_u = __builtin_amdgcn_readfirstlane(g * BB + b);
  float a0 = -__expf(A_log[d * DSN]) * 1.44269504088896f;
  bool ok = ladder_check(A_log, d, a0);
  float w0 = dt_proj_w[2 * d], w1 = dt_proj_w[2 * d + 1], bd = dt_proj_b[d];
  float Dd = Dw[d];
  size_t hb = (size_t)(s_u * NC + chunk) * (DSN * DI) + d;
  const unsigned short* hinus = (const unsigned short*)hin;
  hf2 h2[8];
#pragma unroll
  for (int p2 = 0; p2 < 8; p2++) {
    unsigned lo = hinus[hb + (size_t)(2 * p2) * DI];
    unsigned hi = hinus[hb + (size_t)(2 * p2 + 1) * DI];
    h2[p2] = u2h2(lo | (hi << 16));                // raw f16 bits
  }
  size_t base = (size_t)s_u * LL + (size_t)chunk * CL;
  const unsigned short* up = (const unsigned short*)u_ws + base * DI + d;
  const unsigned* xrow = xdbl + base * XROW;
  // ---- wave-private staging: 32 rows of (dt, B, C) -> LDS (no barrier needed) ----
  int wbc = w * 512, wdt = w * 32;
#pragma unroll
  for (int k = 0; k < 8; k++) {
    int jj2 = k * 64 + d;                          // 0..511
    bcS[wbc + jj2] = xrow[(jj2 >> 4) * XROW + 4 + (jj2 & 15)];
  }
  if (d < 32) dtS[wdt + d] = xrow[d * XROW];
  unsigned short* yout = (unsigned short*)y2S + g * 4224 + (half * CL) * 66 + d;
  if (ok) {
    for (int t = 0; t < CL; t++) {
      unsigned dtp = dtS[wdt + t];
      uint4 bA = *(const uint4*)&bcS[wbc + t * 16];
      uint4 bB = *(const uint4*)&bcS[wbc + t * 16 + 4];
      uint4 cA = *(const uint4*)&bcS[wbc + t * 16 + 8];
      uint4 cB = *(const uint4*)&bcS[wbc + t * 16 + 12];
      float x = fmaf(bhi(dtp), w1, fmaf(blo(dtp), w0, bd));
      float delta = softplus_fast(x);
      float uu = us2f(up[(size_t)t * DI]);
      float du = delta * uu;
      float E = EXP2F(delta * a0);
      float E2 = E * E;
      hf2 e2; e2.x = (_Float16)E; e2.y = (_Float16)E2;
      hf2 E22; E22.x = (_Float16)E2; E22.y = (_Float16)E2;
      _Float16 duh = (_Float16)du;
      hf2 du2; du2.x = duh; du2.y = duh;
      float yacc = 0.f;
      unsigned bw[8] = {bA.x, bA.y, bA.z, bA.w, bB.x, bB.y, bB.z, bB.w};
      unsigned cw[8] = {cA.x, cA.y, cA.z, cA.w, cB.x, cB.y, cB.z, cB.w};
#pragma unroll
      for (int p2 = 0; p2 < 8; p2++) {
        hf2 Bp = u2h2(bw[p2]);
        hf2 Cp = u2h2(cw[p2]);
        h2[p2] = h2[p2] * e2 + Bp * du2;           // pk_mul_f16 + pk_fma_f16
        yacc = FDOT2(h2[p2], Cp, yacc);            // v_dot2_f32_f16
        e2 = e2 * E22;                             // pk_mul_f16
      }
      bf rv = f2bf(yacc + uu * Dd);
      yout[t * 66] = *(unsigned short*)&rv;
    }
  } else {
    f2 A2p[8];
#pragma unroll
    for (int p2 = 0; p2 < 8; p2++) {
      A2p[p2].x = -__expf(A_log[d * DSN + 2 * p2]) * 1.44269504088896f;
      A2p[p2].y = -__expf(A_log[d * DSN + 2 * p2 + 1]) * 1.44269504088896f;
    }
    for (int t = 0; t < CL; t++) {
      unsigned dtp = dtS[wdt + t];
      uint4 bA = *(const uint4*)&bcS[wbc + t * 16];
      uint4 bB = *(const uint4*)&bcS[wbc + t * 16 + 4];
      uint4 cA = *(const uint4*)&bcS[wbc + t * 16 + 8];
      uint4 cB = *(const uint4*)&bcS[wbc + t * 16 + 12];
      float x = fmaf(bhi(dtp), w1, fmaf(blo(dtp), w0, bd));
      float delta = softplus_fast(x);
      float uu = us2f(up[(size_t)t * DI]);
      float du = delta * uu;
      _Float16 duh = (_Float16)du;
      hf2 du2; du2.x = duh; du2.y = duh;
      float yacc = 0.f;
      unsigned bw[8] = {bA.x, bA.y, bA.z, bA.w, bB.x, bB.y, bB.z, bB.w};
      unsigned cw[8] = {cA.x, cA.y, cA.z, cA.w, cB.x, cB.y, cB.z, cB.w};
#pragma unroll
      for (int p2 = 0; p2 < 8; p2++) {
        hf2 ee; ee.x = (_Float16)EXP2F(delta * A2p[p2].x); ee.y = (_Float16)EXP2F(delta * A2p[p2].y);
        hf2 Bp = u2h2(bw[p2]);
        hf2 Cp = u2h2(cw[p2]);
        h2[p2] = h2[p2] * ee + Bp * du2;
        yacc = FDOT2(h2[p2], Cp, yacc);
      }
      bf rv = f2bf(yacc + uu * Dd);
      yout[t * 66] = *(unsigned short*)&rv;
    }
  }
  __syncthreads();
  // ---- z projection (after barrier; acc never lives across the scan) ----
  int p = half;
  int j = d;
  const unsigned short* xnp = (const unsigned short*)xn_ws
                            + ((size_t)(b * CC + g * DM)) * LL + l0b + j;
  float acc[32];                                   // this wave's dd = p*32 .. p*32+31
#pragma unroll
  for (int dd = 0; dd < 32; dd++) acc[dd] = 0.f;
#pragma unroll
  for (int c4 = 0; c4 < 4; c4++) {
    float xc[8];
#pragma unroll
    for (int r8 = 0; r8 < 8; r8++)
      xc[r8] = us2f(xnp[(size_t)(c4 * 8 + r8) * LL]);   // lanes j consecutive -> coalesced
#pragma unroll
    for (int dd = 0; dd < 32; dd++) {              // weights wave-uniform -> s_load
      const float* wz = in_proj_w + (DI + p * 32 + dd) * DM + c4 * 8;
      float a = acc[dd];
#pragma unroll
      for (int r8 = 0; r8 < 8; r8++) a = fmaf(xc[r8], wz[r8], a);
      acc[dd] = a;
    }
  }
  // ---- gate: y3 = y2 * silu(z); own (g,j) row, this wave's dword cols p*16..p*16+15 ----
  const unsigned* yrow = y2S + g * 2112 + j * 33;  // banks (j+k)%32 -> conflict-free
#pragma unroll
  for (int kk = 0; kk < 16; kk++) {
    unsigned v = yrow[p * 16 + kk];
    float z0 = acc[2 * kk], z1 = acc[2 * kk + 1];
    acc[2 * kk]     = blo(v) * (z0 * sigmoidf_(z0));
    acc[2 * kk + 1] = bhi(v) * (z1 * sigmoidf_(z1));
  }
  __syncthreads();                                 // y2S fully consumed -> reuse as partials
  // ---- phase A: partials for the OTHER wave's jj half (both waves work) ----
  float* prow = (float*)y2S + g * 2112 + j * 33;   // stride-33 -> conflict-free
  int jjb = (1 - p) * 16;
#pragma unroll
  for (int jj = 0; jj < 16; jj++) {
    const float* wo = out_proj_w + (jjb + jj) * DI + p * 32;
    float a = 0.f;
#pragma unroll
    for (int dd = 0; dd < 32; dd++) a = fmaf(acc[dd], wo[dd], a);
    prow[jjb + jj] = a;
  }
  __syncthreads();
  // ---- phase B: finalize own half (partial + own dot + residual), store 16 rows/wave ----
  int jf = p * 16;
  float* ob = out + ((size_t)(b * CC + g * DM)) * LL + l0b + j;
#pragma unroll
  for (int jj = 0; jj < 16; jj++) {
    const float* wo = out_proj_w + (jf + jj) * DI + p * 32;
    float a = us2f(xnp[(size_t)(jf + jj) * LL]) + prow[jf + jj];
#pragma unroll
    for (int dd = 0; dd < 32; dd++) a = fmaf(acc[dd], wo[dd], a);
    ob[(size_t)(jf + jj) * LL] = a;                // coalesced 256B
  }
}

extern "C" void kernel_launch(void* const* d_in, const int* in_sizes, int n_in,
                              void* d_out, int out_size, void* d_ws, size_t ws_size,
                              hipStream_t stream) {
  const float* input     = (const float*)d_in[0];
  const float* ln_g      = (const float*)d_in[1];
  const float* ln_b      = (const float*)d_in[2];
  const float* in_proj_w = (const float*)d_in[3];
  const float* conv_w    = (const float*)d_in[4];
  const float* conv_b    = (const float*)d_in[5];
  const float* x_proj_w  = (const float*)d_in[6];
  const float* dt_proj_w = (const float*)d_in[7];
  const float* dt_proj_b = (const float*)d_in[8];
  const float* A_log     = (const float*)d_in[9];
  const float* Dw        = (const float*)d_in[10];
  const float* out_proj_w= (const float*)d_in[11];
  float* out = (float*)d_out;

  char* ws = (char*)d_ws;
  bf*       u_ws  = (bf*)(ws);                    // 32 MiB
  unsigned* xdbl  = (unsigned*)(ws + 33554432);   // 20 MiB
  bf*       xn_ws = (bf*)(ws + 54525952);         // 16 MiB
  __half*   hloc  = (__half*)(ws + 71303168);     // 16 MiB fp16 (NC=128; hin aliases after k4)
  __half*   ssum  = (__half*)(ws + 88080384);     // 1 MiB fp16 (total 89,128,960 B — known-good)
  (void)in_sizes; (void)n_in; (void)out_size; (void)ws_size;

  hipLaunchKernelGGL(k1_ln_conv, dim3(BB * NT), dim3(256), 0, stream,
                     input, ln_g, ln_b, in_proj_w, conv_w, conv_b, u_ws, xn_ws);
  hipLaunchKernelGGL(k2_xproj, dim3(1024), dim3(256), 0, stream,
                     u_ws, x_proj_w, xdbl);
  hipLaunchKernelGGL(k3_scanA, dim3(GG * NC / 4), dim3(256), 0, stream,
                     xdbl, u_ws, A_log, dt_proj_w, dt_proj_b, hloc, ssum);
  hipLaunchKernelGGL(k4_combine, dim3(GG), dim3(1024), 0, stream,
                     ssum, A_log, hloc);
  hipLaunchKernelGGL(k56_scan_final, dim3(BB * NC / 2), dim3(512), 0, stream,
                     xdbl, u_ws, A_log, dt_proj_w, dt_proj_b, Dw, hloc, xn_ws,
                     in_proj_w, out_proj_w, out);
}

// Round 11
// 364.115 us; speedup vs baseline: 1.0199x; 1.0098x over previous
//
#include <hip/hip_runtime.h>
#include <hip/hip_bf16.h>
#include <hip/hip_fp16.h>
#include <math.h>

typedef __hip_bfloat16 bf;
typedef float f2 __attribute__((ext_vector_type(2)));
typedef _Float16 hf2 __attribute__((ext_vector_type(2)));

#define BB   16     // batch
#define CC   128    // channels
#define LL   4096   // H*W
#define DM   32     // d_model per chunk
#define DI   64     // d_inner
#define DSN  16     // d_state
#define GG   64     // 4 * BB sequences
#define NC   128    // scan chunks (CL=32)
#define CL   32     // LL / NC
#define TLV  61     // valid output columns per k1 tile (64 loaded, 3 head)
#define NT   68     // ceil(LL / TLV)
#define XS   133    // k1 xnT row stride in dwords (odd -> conflict-free)
#define YS   35     // k1 xiS row stride in dwords
#define XROW 20     // xdbl row stride in dwords (80 B: dw0=dt01 bf16, dw1-3 pad, dw4-11=B f16, dw12-19=C f16)

__device__ __forceinline__ float bf2f(bf x) { return __bfloat162float(x); }
__device__ __forceinline__ bf f2bf(float x) { return __float2bfloat16(x); }
__device__ __forceinline__ float blo(unsigned v) { return __uint_as_float(v << 16); }
__device__ __forceinline__ float bhi(unsigned v) { return __uint_as_float(v & 0xffff0000u); }
__device__ __forceinline__ float us2f(unsigned short v) { return __uint_as_float((unsigned)v << 16); }
__device__ __forceinline__ unsigned pack2(float a, float b) {
  bf ba = f2bf(a), bb = f2bf(b);
  unsigned short ua = *(unsigned short*)&ba, ub = *(unsigned short*)&bb;
  return (unsigned)ua | ((unsigned)ub << 16);
}
// f16 pair pack (k2 emits B/C as f16 so the scan consumes them with NO unpack)
__device__ __forceinline__ unsigned pack2h(float a, float b) {
  _Float16 ha = (_Float16)a, hb = (_Float16)b;
  unsigned short ua = *(unsigned short*)&ha, ub = *(unsigned short*)&hb;
  return (unsigned)ua | ((unsigned)ub << 16);
}
__device__ __forceinline__ hf2 u2h2(unsigned v) {
  union { unsigned u; hf2 h; } c; c.u = v; return c.h;
}

#if __has_builtin(__builtin_amdgcn_exp2f)
#define EXP2F(x) __builtin_amdgcn_exp2f(x)
#else
#define EXP2F(x) exp2f(x)
#endif

#if __has_builtin(__builtin_amdgcn_fdot2)
#define FDOT2(a, b, c) __builtin_amdgcn_fdot2((a), (b), (c), false)
#else
#define FDOT2(a, b, c) ((c) + (float)(a).x * (float)(b).x + (float)(a).y * (float)(b).y)
#endif

__device__ __forceinline__ float sigmoidf_(float x) { return 1.0f / (1.0f + __expf(-x)); }
// fast softplus: max(x,0) + ln2 * log2(1 + exp2(-|x|*log2e))
__device__ __forceinline__ float softplus_fast(float x) {
  float t = EXP2F(-fabsf(x) * 1.44269504088896f);
  return fmaxf(x, 0.0f) + 0.69314718056f * __log2f(1.0f + t);
}

// ---------------- K1: layernorm + in_proj(xi) + causal conv + silu -> u (bf16), xn (bf16) ----------------
// (unchanged)
__global__ __launch_bounds__(256, 4) void k1_ln_conv(
    const float* __restrict__ input, const float* __restrict__ ln_g, const float* __restrict__ ln_b,
    const float* __restrict__ in_proj_w, const float* __restrict__ conv_w, const float* __restrict__ conv_b,
    bf* __restrict__ u_ws, bf* __restrict__ xn_ws) {
  __shared__ unsigned ldsbuf[8960];               // union: xnT fp32 64x133dw / xiS bf16 256x35dw
  __shared__ float mu_s[64], rs_s[64];
  float* xnT = (float*)ldsbuf;
  unsigned short* xiS = (unsigned short*)ldsbuf;
  int b = blockIdx.x / NT;
  int tile = blockIdx.x - b * NT;
  int l0 = tile * TLV;
  int tid = threadIdx.x;
  const float* inb = input + (size_t)b * CC * LL;
#pragma unroll
  for (int k = 0; k < 32; k++) {
    int i = tid + k * 256;
    int j = i & 63, c = i >> 6;
    int l = l0 - 3 + j;
    xnT[j * XS + c] = (l >= 0 && l < LL) ? inb[c * LL + l] : 0.0f;
  }
  __syncthreads();
  if (tid < 64) {
    float s = 0.f, s2 = 0.f;
    for (int c = 0; c < CC; c++) { float v = xnT[tid * XS + c]; s += v; s2 = fmaf(v, v, s2); }
    float mu = s * (1.0f / CC);
    float var = s2 * (1.0f / CC) - mu * mu;
    mu_s[tid] = mu;
    rs_s[tid] = rsqrtf(var + 1e-5f);
  }
  __syncthreads();
#pragma unroll
  for (int k = 0; k < 32; k++) {
    int i = tid + k * 256;
    int j = i & 63, c = i >> 6;
    xnT[j * XS + c] = (xnT[j * XS + c] - mu_s[j]) * rs_s[j] * ln_g[c] + ln_b[c];
  }
  __syncthreads();
  for (int i = tid; i < CC * TLV; i += 256) {
    int c = i / TLV, j2 = i - c * TLV;
    int l = l0 + j2;
    if (l < LL) xn_ws[((size_t)(b * CC + c)) * LL + l] = f2bf(xnT[(j2 + 3) * XS + c]);
  }
  int g = tid >> 6, j = tid & 63;
  float xr[32];
#pragma unroll
  for (int r = 0; r < 32; r++) xr[r] = xnT[j * XS + g * DM + r];
  bool zero_col = (l0 - 3 + j < 0);
  __syncthreads();
#pragma unroll
  for (int c2 = 0; c2 < 4; c2++) {
    float acc[16];
#pragma unroll
    for (int dd = 0; dd < 16; dd++) {
      const float* w = in_proj_w + (c2 * 16 + dd) * DM;
      float a = 0.f;
#pragma unroll
      for (int r = 0; r < 32; r++) a = fmaf(xr[r], w[r], a);
      acc[dd] = zero_col ? 0.f : a;
    }
    unsigned* xo = (unsigned*)&ldsbuf[(g * 64 + j) * YS + c2 * 8];
#pragma unroll
    for (int k = 0; k < 8; k++)
      xo[k] = pack2(acc[2 * k], acc[2 * k + 1]);
  }
  __syncthreads();
  int d = j;
  float cw0 = conv_w[d * 4 + 0], cw1 = conv_w[d * 4 + 1];
  float cw2 = conv_w[d * 4 + 2], cw3 = conv_w[d * 4 + 3];
  float cb = conv_b[d];
  bf* uo = u_ws + (size_t)(g * BB + b) * LL * DI + d;
  float x3 = 0.f, x2 = 0.f, x1 = 0.f, x0 = 0.f;
  for (int jj = 0; jj < 64; jj++) {
    float xi = us2f(xiS[(g * 64 + jj) * (2 * YS) + d]);
    x3 = x2; x2 = x1; x1 = x0; x0 = xi;
    int l = l0 + jj - 3;
    if (jj >= 3 && l < LL) {
      float pre = x3 * cw0 + x2 * cw1 + x1 * cw2 + x0 * cw3 + cb;
      float uu = pre * sigmoidf_(pre);
      uo[(size_t)l * DI] = f2bf(uu);
    }
  }
}

// ---------------- K2: x_proj only -> xdbl rows (dt bf16; B,C packed f16) ----------------
// (unchanged from round 10)
__global__ __launch_bounds__(256) void k2_xproj(
    const bf* __restrict__ u_ws, const float* __restrict__ x_proj_w,
    unsigned* __restrict__ xdbl) {
  __shared__ unsigned uS[256 * 33];
  int tid = threadIdx.x;
  size_t pos0 = (size_t)blockIdx.x * 256;
  const unsigned* src = (const unsigned*)u_ws + pos0 * 32;
#pragma unroll
  for (int k = 0; k < 32; k++) {
    int idx = tid + k * 256;
    uS[(idx >> 5) * 33 + (idx & 31)] = src[idx];
  }
  __syncthreads();
  float xdb[34];
#pragma unroll
  for (int e = 0; e < 34; e++) xdb[e] = 0.f;
#pragma unroll
  for (int c2 = 0; c2 < 4; c2++) {
    float f[16];
#pragma unroll
    for (int k = 0; k < 8; k++) {
      unsigned v = uS[tid * 33 + c2 * 8 + k];
      f[2 * k] = blo(v); f[2 * k + 1] = bhi(v);
    }
#pragma unroll
    for (int e = 0; e < 34; e++) {
      const float* w = x_proj_w + e * DI + c2 * 16;
      float a = xdb[e];
#pragma unroll
      for (int i = 0; i < 16; i++) a = fmaf(f[i], w[i], a);
      xdb[e] = a;
    }
  }
  unsigned* row = &uS[tid * 33];
  row[0] = pack2(xdb[0], xdb[1]);
#pragma unroll
  for (int n = 0; n < 8; n++) row[4 + n]  = pack2h(xdb[2 + 2 * n], xdb[3 + 2 * n]);
#pragma unroll
  for (int n = 0; n < 8; n++) row[12 + n] = pack2h(xdb[18 + 2 * n], xdb[19 + 2 * n]);
  __syncthreads();
  unsigned* dst = xdbl + pos0 * XROW;
#pragma unroll
  for (int k = 0; k < XROW; k++) {
    int idx = tid + k * 256;
    int r = idx / XROW, c = idx - r * XROW;
    dst[idx] = uS[r * 33 + c];
  }
}

// A2[n] == (n+1)*A2[0] for this problem's A = arange(1..16); guarded fast path.
__device__ __forceinline__ bool ladder_check(const float* A_log, int d, float a0) {
  bool ok = true;
#pragma unroll
  for (int n = 1; n < DSN; n++) {
    float an = -__expf(A_log[d * DSN + n]) * 1.44269504088896f;
    ok = ok && (fabsf(an / a0 - (float)(n + 1)) < 1e-3f);
  }
  return ok;
}

// ---------------- K3: scan pass A — local states + chunk delta-sums ----------------
// (unchanged from round 10)
__global__ __launch_bounds__(256, 8) void k3_scanA(
    const unsigned* __restrict__ xdbl, const bf* __restrict__ u_ws,
    const float* __restrict__ A_log, const float* __restrict__ dt_proj_w,
    const float* __restrict__ dt_proj_b,
    __half* __restrict__ hloc, __half* __restrict__ ssum_ws) {
  __shared__ __align__(16) unsigned bS3[4 * 256];  // per-wave 32 rows x 8 dw (B f16)
  __shared__ unsigned dtS3[4 * 32];                // per-wave 32 rows dt
  int tid = threadIdx.x;
  int wv = __builtin_amdgcn_readfirstlane(tid >> 6);            // wave in block 0..3
  int wid = __builtin_amdgcn_readfirstlane(blockIdx.x * 4 + wv); // linear (s,chunk)
  int s = wid >> 7, chunk = wid & (NC - 1);
  int d = tid & 63;
  float a0 = -__expf(A_log[d * DSN]) * 1.44269504088896f;
  bool ok = ladder_check(A_log, d, a0);
  float w0 = dt_proj_w[2 * d], w1 = dt_proj_w[2 * d + 1], bd = dt_proj_b[d];
  hf2 h2[8];
#pragma unroll
  for (int p2 = 0; p2 < 8; p2++) h2[p2] = u2h2(0u);
  float ss = 0.f;
  size_t base = (size_t)s * LL + (size_t)chunk * CL;
  const unsigned short* up = (const unsigned short*)u_ws + base * DI + d;
  const unsigned* xrow = xdbl + base * XROW;
  // ---- wave-private staging: 32 rows of (dt, B) -> LDS (no barrier needed) ----
  int wb = wv * 256, wd3 = wv * 32;
#pragma unroll
  for (int k = 0; k < 4; k++) {
    int jj2 = k * 64 + d;                          // 0..255
    bS3[wb + jj2] = xrow[(jj2 >> 3) * XROW + 4 + (jj2 & 7)];
  }
  if (d < 32) dtS3[wd3 + d] = xrow[d * XROW];
  if (ok) {
    for (int t = 0; t < CL; t++) {
      unsigned dtp = dtS3[wd3 + t];
      uint4 bA = *(const uint4*)&bS3[wb + t * 8];
      uint4 bB = *(const uint4*)&bS3[wb + t * 8 + 4];
      float x = fmaf(bhi(dtp), w1, fmaf(blo(dtp), w0, bd));
      float delta = softplus_fast(x);
      float uu = us2f(up[(size_t)t * DI]);
      float du = delta * uu;
      ss += delta;
      float E = EXP2F(delta * a0);
      float E2 = E * E;
      hf2 e2; e2.x = (_Float16)E; e2.y = (_Float16)E2;
      hf2 E22; E22.x = (_Float16)E2; E22.y = (_Float16)E2;
      _Float16 duh = (_Float16)du;
      hf2 du2; du2.x = duh; du2.y = duh;
      unsigned bw[8] = {bA.x, bA.y, bA.z, bA.w, bB.x, bB.y, bB.z, bB.w};
#pragma unroll
      for (int p2 = 0; p2 < 8; p2++) {
        hf2 Bp = u2h2(bw[p2]);
        h2[p2] = h2[p2] * e2 + Bp * du2;           // v_pk_mul_f16 + v_pk_fma_f16
        e2 = e2 * E22;                             // v_pk_mul_f16
      }
    }
  } else {
    f2 A2p[8];
#pragma unroll
    for (int p2 = 0; p2 < 8; p2++) {
      A2p[p2].x = -__expf(A_log[d * DSN + 2 * p2]) * 1.44269504088896f;
      A2p[p2].y = -__expf(A_log[d * DSN + 2 * p2 + 1]) * 1.44269504088896f;
    }
    for (int t = 0; t < CL; t++) {
      unsigned dtp = dtS3[wd3 + t];
      uint4 bA = *(const uint4*)&bS3[wb + t * 8];
      uint4 bB = *(const uint4*)&bS3[wb + t * 8 + 4];
      float x = fmaf(bhi(dtp), w1, fmaf(blo(dtp), w0, bd));
      float delta = softplus_fast(x);
      float uu = us2f(up[(size_t)t * DI]);
      float du = delta * uu;
      ss += delta;
      _Float16 duh = (_Float16)du;
      hf2 du2; du2.x = duh; du2.y = duh;
      unsigned bw[8] = {bA.x, bA.y, bA.z, bA.w, bB.x, bB.y, bB.z, bB.w};
#pragma unroll
      for (int p2 = 0; p2 < 8; p2++) {
        hf2 ee; ee.x = (_Float16)EXP2F(delta * A2p[p2].x); ee.y = (_Float16)EXP2F(delta * A2p[p2].y);
        hf2 Bp = u2h2(bw[p2]);
        h2[p2] = h2[p2] * ee + Bp * du2;
      }
    }
  }
  size_t ob = (size_t)wid * (DSN * DI) + d;
  unsigned short* hl = (unsigned short*)hloc;
#pragma unroll
  for (int n = 0; n < DSN; n++) {
    _Float16 v = (n & 1) ? h2[n >> 1].y : h2[n >> 1].x;
    hl[ob + n * DI] = *(unsigned short*)&v;        // raw f16 bits (hloc is fp16)
  }
  ssum_ws[wid * DI + d] = __float2half(ss);
}

// ---------------- K4: cross-chunk combine ----------------
// Round-11 rewrite. Old launch: 64 blocks x 1024 threads = 64 CUs busy (192 IDLE),
// 1 wave/SIMD, and a load->store->fma pointer chase with no explicit pipelining
// (~600 cyc latency x 128 serial iters). New: 256 blocks x 256 threads (every CU
// gets a block) + group-of-4 double-buffered prefetch: group k+1's hl/ss loads are
// in flight while group k computes. load(k) still precedes store(k) for every k.
__global__ __launch_bounds__(256) void k4_combine(
    const __half* __restrict__ ssum_ws, const float* __restrict__ A_log, __half* hloc_hin) {
  int s = blockIdx.x >> 2;                         // 0..63
  int q = blockIdx.x & 3;                          // n-quarter
  int tid = threadIdx.x;
  int n = q * 4 + (tid >> 6);                      // 0..15
  int d = tid & 63;
  float A2 = -__expf(A_log[d * DSN + n]) * 1.44269504088896f;
  float h = 0.f;
  const __half* sp = ssum_ws + (size_t)s * NC * DI + d;
  __half* hp = hloc_hin + (size_t)s * NC * (DSN * DI) + n * DI + d;
  float hl[4], ssv[4], hln[4], ssn[4];
#pragma unroll
  for (int j = 0; j < 4; j++) {
    hln[j] = __half2float(hp[(size_t)j * (DSN * DI)]);
    ssn[j] = __half2float(sp[j * DI]);
  }
  for (int kb = 0; kb < NC / 4; kb++) {
#pragma unroll
    for (int j = 0; j < 4; j++) { hl[j] = hln[j]; ssv[j] = ssn[j]; }
    if (kb + 1 < NC / 4) {
#pragma unroll
      for (int j = 0; j < 4; j++) {
        int k = (kb + 1) * 4 + j;
        hln[j] = __half2float(hp[(size_t)k * (DSN * DI)]);
        ssn[j] = __half2float(sp[k * DI]);
      }
    }
#pragma unroll
    for (int j = 0; j < 4; j++) {
      int k = kb * 4 + j;
      float ap = EXP2F(A2 * ssv[j]);
      hp[(size_t)k * (DSN * DI)] = __float2half(h);
      h = fmaf(h, ap, hl[j]);
    }
  }
}

// ---------------- K56: scan pass C (y2 -> LDS) + z-gate + out_proj + residual -> output (fp32) ----------------
// (unchanged from round 10 — 4 rounds of micro-opt all land ~112 µs; declared floored)
__global__ __launch_bounds__(512, 4) void k56_scan_final(
    const unsigned* __restrict__ xdbl, const bf* __restrict__ u_ws,
    const float* __restrict__ A_log, const float* __restrict__ dt_proj_w,
    const float* __restrict__ dt_proj_b, const float* __restrict__ Dw,
    const __half* __restrict__ hin, const bf* __restrict__ xn_ws,
    const float* __restrict__ in_proj_w, const float* __restrict__ out_proj_w,
    float* __restrict__ out) {
  __shared__ unsigned y2S[4 * 64 * 33];            // 33792 B: per-g 64 rows x 33 dw
  __shared__ __align__(16) unsigned bcS[8 * 512];  // 16384 B: per-wave 32 rows x 16 dw (B,C f16)
  __shared__ unsigned dtS[8 * 32];                 // 1024 B: per-wave 32 rows dt
  int b = blockIdx.x >> 6;
  int cpair = blockIdx.x & 63;                     // 64 col-tiles of 64
  int l0b = cpair * 64;                            // block's first output column
  int tid = threadIdx.x;
  int w = __builtin_amdgcn_readfirstlane(tid >> 6); // 0..7
  int g = w >> 1, half = w & 1;
  int d = tid & 63;
  int chunk = cpair * 2 + half;                    // scalar
  int s_u = __builtin_amdgcn_readfirstlane(g * BB + b);
  float a0 = -__expf(A_log[d * DSN]) * 1.44269504088896f;
  bool ok = ladder_check(A_log, d, a0);
  float w0 = dt_proj_w[2 * d], w1 = dt_proj_w[2 * d + 1], bd = dt_proj_b[d];
  float Dd = Dw[d];
  size_t hb = (size_t)(s_u * NC + chunk) * (DSN * DI) + d;
  const unsigned short* hinus = (const unsigned short*)hin;
  hf2 h2[8];
#pragma unroll
  for (int p2 = 0; p2 < 8; p2++) {
    unsigned lo = hinus[hb + (size_t)(2 * p2) * DI];
    unsigned hi = hinus[hb + (size_t)(2 * p2 + 1) * DI];
    h2[p2] = u2h2(lo | (hi << 16));                // raw f16 bits
  }
  size_t base = (size_t)s_u * LL + (size_t)chunk * CL;
  const unsigned short* up = (const unsigned short*)u_ws + base * DI + d;
  const unsigned* xrow = xdbl + base * XROW;
  // ---- wave-private staging: 32 rows of (dt, B, C) -> LDS (no barrier needed) ----
  int wbc = w * 512, wdt = w * 32;
#pragma unroll
  for (int k = 0; k < 8; k++) {
    int jj2 = k * 64 + d;                          // 0..511
    bcS[wbc + jj2] = xrow[(jj2 >> 4) * XROW + 4 + (jj2 & 15)];
  }
  if (d < 32) dtS[wdt + d] = xrow[d * XROW];
  unsigned short* yout = (unsigned short*)y2S + g * 4224 + (half * CL) * 66 + d;
  if (ok) {
    for (int t = 0; t < CL; t++) {
      unsigned dtp = dtS[wdt + t];
      uint4 bA = *(const uint4*)&bcS[wbc + t * 16];
      uint4 bB = *(const uint4*)&bcS[wbc + t * 16 + 4];
      uint4 cA = *(const uint4*)&bcS[wbc + t * 16 + 8];
      uint4 cB = *(const uint4*)&bcS[wbc + t * 16 + 12];
      float x = fmaf(bhi(dtp), w1, fmaf(blo(dtp), w0, bd));
      float delta = softplus_fast(x);
      float uu = us2f(up[(size_t)t * DI]);
      float du = delta * uu;
      float E = EXP2F(delta * a0);
      float E2 = E * E;
      hf2 e2; e2.x = (_Float16)E; e2.y = (_Float16)E2;
      hf2 E22; E22.x = (_Float16)E2; E22.y = (_Float16)E2;
      _Float16 duh = (_Float16)du;
      hf2 du2; du2.x = duh; du2.y = duh;
      float yacc = 0.f;
      unsigned bw[8] = {bA.x, bA.y, bA.z, bA.w, bB.x, bB.y, bB.z, bB.w};
      unsigned cw[8] = {cA.x, cA.y, cA.z, cA.w, cB.x, cB.y, cB.z, cB.w};
#pragma unroll
      for (int p2 = 0; p2 < 8; p2++) {
        hf2 Bp = u2h2(bw[p2]);
        hf2 Cp = u2h2(cw[p2]);
        h2[p2] = h2[p2] * e2 + Bp * du2;           // pk_mul_f16 + pk_fma_f16
        yacc = FDOT2(h2[p2], Cp, yacc);            // v_dot2_f32_f16
        e2 = e2 * E22;                             // pk_mul_f16
      }
      bf rv = f2bf(yacc + uu * Dd);
      yout[t * 66] = *(unsigned short*)&rv;
    }
  } else {
    f2 A2p[8];
#pragma unroll
    for (int p2 = 0; p2 < 8; p2++) {
      A2p[p2].x = -__expf(A_log[d * DSN + 2 * p2]) * 1.44269504088896f;
      A2p[p2].y = -__expf(A_log[d * DSN + 2 * p2 + 1]) * 1.44269504088896f;
    }
    for (int t = 0; t < CL; t++) {
      unsigned dtp = dtS[wdt + t];
      uint4 bA = *(const uint4*)&bcS[wbc + t * 16];
      uint4 bB = *(const uint4*)&bcS[wbc + t * 16 + 4];
      uint4 cA = *(const uint4*)&bcS[wbc + t * 16 + 8];
      uint4 cB = *(const uint4*)&bcS[wbc + t * 16 + 12];
      float x = fmaf(bhi(dtp), w1, fmaf(blo(dtp), w0, bd));
      float delta = softplus_fast(x);
      float uu = us2f(up[(size_t)t * DI]);
      float du = delta * uu;
      _Float16 duh = (_Float16)du;
      hf2 du2; du2.x = duh; du2.y = duh;
      float yacc = 0.f;
      unsigned bw[8] = {bA.x, bA.y, bA.z, bA.w, bB.x, bB.y, bB.z, bB.w};
      unsigned cw[8] = {cA.x, cA.y, cA.z, cA.w, cB.x, cB.y, cB.z, cB.w};
#pragma unroll
      for (int p2 = 0; p2 < 8; p2++) {
        hf2 ee; ee.x = (_Float16)EXP2F(delta * A2p[p2].x); ee.y = (_Float16)EXP2F(delta * A2p[p2].y);
        hf2 Bp = u2h2(bw[p2]);
        hf2 Cp = u2h2(cw[p2]);
        h2[p2] = h2[p2] * ee + Bp * du2;
        yacc = FDOT2(h2[p2], Cp, yacc);
      }
      bf rv = f2bf(yacc + uu * Dd);
      yout[t * 66] = *(unsigned short*)&rv;
    }
  }
  __syncthreads();
  // ---- z projection (after barrier; acc never lives across the scan) ----
  int p = half;
  int j = d;
  const unsigned short* xnp = (const unsigned short*)xn_ws
                            + ((size_t)(b * CC + g * DM)) * LL + l0b + j;
  float acc[32];                                   // this wave's dd = p*32 .. p*32+31
#pragma unroll
  for (int dd = 0; dd < 32; dd++) acc[dd] = 0.f;
#pragma unroll
  for (int c4 = 0; c4 < 4; c4++) {
    float xc[8];
#pragma unroll
    for (int r8 = 0; r8 < 8; r8++)
      xc[r8] = us2f(xnp[(size_t)(c4 * 8 + r8) * LL]);   // lanes j consecutive -> coalesced
#pragma unroll
    for (int dd = 0; dd < 32; dd++) {              // weights wave-uniform -> s_load
      const float* wz = in_proj_w + (DI + p * 32 + dd) * DM + c4 * 8;
      float a = acc[dd];
#pragma unroll
      for (int r8 = 0; r8 < 8; r8++) a = fmaf(xc[r8], wz[r8], a);
      acc[dd] = a;
    }
  }
  // ---- gate: y3 = y2 * silu(z); own (g,j) row, this wave's dword cols p*16..p*16+15 ----
  const unsigned* yrow = y2S + g * 2112 + j * 33;  // banks (j+k)%32 -> conflict-free
#pragma unroll
  for (int kk = 0; kk < 16; kk++) {
    unsigned v = yrow[p * 16 + kk];
    float z0 = acc[2 * kk], z1 = acc[2 * kk + 1];
    acc[2 * kk]     = blo(v) * (z0 * sigmoidf_(z0));
    acc[2 * kk + 1] = bhi(v) * (z1 * sigmoidf_(z1));
  }
  __syncthreads();                                 // y2S fully consumed -> reuse as partials
  // ---- phase A: partials for the OTHER wave's jj half (both waves work) ----
  float* prow = (float*)y2S + g * 2112 + j * 33;   // stride-33 -> conflict-free
  int jjb = (1 - p) * 16;
#pragma unroll
  for (int jj = 0; jj < 16; jj++) {
    const float* wo = out_proj_w + (jjb + jj) * DI + p * 32;
    float a = 0.f;
#pragma unroll
    for (int dd = 0; dd < 32; dd++) a = fmaf(acc[dd], wo[dd], a);
    prow[jjb + jj] = a;
  }
  __syncthreads();
  // ---- phase B: finalize own half (partial + own dot + residual), store 16 rows/wave ----
  int jf = p * 16;
  float* ob = out + ((size_t)(b * CC + g * DM)) * LL + l0b + j;
#pragma unroll
  for (int jj = 0; jj < 16; jj++) {
    const float* wo = out_proj_w + (jf + jj) * DI + p * 32;
    float a = us2f(xnp[(size_t)(jf + jj) * LL]) + prow[jf + jj];
#pragma unroll
    for (int dd = 0; dd < 32; dd++) a = fmaf(acc[dd], wo[dd], a);
    ob[(size_t)(jf + jj) * LL] = a;                // coalesced 256B
  }
}

extern "C" void kernel_launch(void* const* d_in, const int* in_sizes, int n_in,
                              void* d_out, int out_size, void* d_ws, size_t ws_size,
                              hipStream_t stream) {
  const float* input     = (const float*)d_in[0];
  const float* ln_g      = (const float*)d_in[1];
  const float* ln_b      = (const float*)d_in[2];
  const float* in_proj_w = (const float*)d_in[3];
  const float* conv_w    = (const float*)d_in[4];
  const float* conv_b    = (const float*)d_in[5];
  const float* x_proj_w  = (const float*)d_in[6];
  const float* dt_proj_w = (const float*)d_in[7];
  const float* dt_proj_b = (const float*)d_in[8];
  const float* A_log     = (const float*)d_in[9];
  const float* Dw        = (const float*)d_in[10];
  const float* out_proj_w= (const float*)d_in[11];
  float* out = (float*)d_out;

  char* ws = (char*)d_ws;
  bf*       u_ws  = (bf*)(ws);                    // 32 MiB
  unsigned* xdbl  = (unsigned*)(ws + 33554432);   // 20 MiB
  bf*       xn_ws = (bf*)(ws + 54525952);         // 16 MiB
  __half*   hloc  = (__half*)(ws + 71303168);     // 16 MiB fp16 (NC=128; hin aliases after k4)
  __half*   ssum  = (__half*)(ws + 88080384);     // 1 MiB fp16 (total 89,128,960 B — known-good)
  (void)in_sizes; (void)n_in; (void)out_size; (void)ws_size;

  hipLaunchKernelGGL(k1_ln_conv, dim3(BB * NT), dim3(256), 0, stream,
                     input, ln_g, ln_b, in_proj_w, conv_w, conv_b, u_ws, xn_ws);
  hipLaunchKernelGGL(k2_xproj, dim3(1024), dim3(256), 0, stream,
                     u_ws, x_proj_w, xdbl);
  hipLaunchKernelGGL(k3_scanA, dim3(GG * NC / 4), dim3(256), 0, stream,
                     xdbl, u_ws, A_log, dt_proj_w, dt_proj_b, hloc, ssum);
  hipLaunchKernelGGL(k4_combine, dim3(GG * 4), dim3(256), 0, stream,
                     ssum, A_log, hloc);
  hipLaunchKernelGGL(k56_scan_final, dim3(BB * NC / 2), dim3(512), 0, stream,
                     xdbl, u_ws, A_log, dt_proj_w, dt_proj_b, Dw, hloc, xn_ws,
                     in_proj_w, out_proj_w, out);
}

// Round 13
// 350.216 us; speedup vs baseline: 1.0604x; 1.0397x over previous
//
#include <hip/hip_runtime.h>
#include <hip/hip_bf16.h>
#include <hip/hip_fp16.h>
#include <math.h>

typedef __hip_bfloat16 bf;
typedef float f2 __attribute__((ext_vector_type(2)));
typedef _Float16 hf2 __attribute__((ext_vector_type(2)));

#define BB   16     // batch
#define CC   128    // channels
#define LL   4096   // H*W
#define DM   32     // d_model per chunk
#define DI   64     // d_inner
#define DSN  16     // d_state
#define GG   64     // 4 * BB sequences
#define NC   128    // scan chunks (CL=32)
#define CL   32     // LL / NC
#define TLV  61     // valid output columns per k1 tile (64 loaded, 3 head)
#define NT   68     // ceil(LL / TLV)
#define XS   133    // k1 xnT row stride in dwords (odd -> conflict-free)
#define YS   35     // k1 xiS row stride in dwords
#define XROW 20     // xdbl row stride in dwords (80 B: dw0=dt01 bf16, dw1-3 pad, dw4-11=B f16, dw12-19=C f16)

__device__ __forceinline__ float bf2f(bf x) { return __bfloat162float(x); }
__device__ __forceinline__ bf f2bf(float x) { return __float2bfloat16(x); }
__device__ __forceinline__ float blo(unsigned v) { return __uint_as_float(v << 16); }
__device__ __forceinline__ float bhi(unsigned v) { return __uint_as_float(v & 0xffff0000u); }
__device__ __forceinline__ float us2f(unsigned short v) { return __uint_as_float((unsigned)v << 16); }
__device__ __forceinline__ unsigned pack2(float a, float b) {
  bf ba = f2bf(a), bb = f2bf(b);
  unsigned short ua = *(unsigned short*)&ba, ub = *(unsigned short*)&bb;
  return (unsigned)ua | ((unsigned)ub << 16);
}
// f16 pair pack (k2 emits B/C as f16 so the scan consumes them with NO unpack)
__device__ __forceinline__ unsigned pack2h(float a, float b) {
  _Float16 ha = (_Float16)a, hb = (_Float16)b;
  unsigned short ua = *(unsigned short*)&ha, ub = *(unsigned short*)&hb;
  return (unsigned)ua | ((unsigned)ub << 16);
}
__device__ __forceinline__ hf2 u2h2(unsigned v) {
  union { unsigned u; hf2 h; } c; c.u = v; return c.h;
}

#if __has_builtin(__builtin_amdgcn_exp2f)
#define EXP2F(x) __builtin_amdgcn_exp2f(x)
#else
#define EXP2F(x) exp2f(x)
#endif

#if __has_builtin(__builtin_amdgcn_fdot2)
#define FDOT2(a, b, c) __builtin_amdgcn_fdot2((a), (b), (c), false)
#else
#define FDOT2(a, b, c) ((c) + (float)(a).x * (float)(b).x + (float)(a).y * (float)(b).y)
#endif

__device__ __forceinline__ float sigmoidf_(float x) { return 1.0f / (1.0f + __expf(-x)); }
// fast softplus: max(x,0) + ln2 * log2(1 + exp2(-|x|*log2e))
__device__ __forceinline__ float softplus_fast(float x) {
  float t = EXP2F(-fabsf(x) * 1.44269504088896f);
  return fmaxf(x, 0.0f) + 0.69314718056f * __log2f(1.0f + t);
}

// A2[n] == (n+1)*A2[0] for this problem's A = arange(1..16); guarded fast path.
__device__ __forceinline__ bool ladder_check(const float* A_log, int d, float a0) {
  bool ok = true;
#pragma unroll
  for (int n = 1; n < DSN; n++) {
    float an = -__expf(A_log[d * DSN + n]) * 1.44269504088896f;
    ok = ok && (fabsf(an / a0 - (float)(n + 1)) < 1e-3f);
  }
  return ok;
}

// ---------------- K1: layernorm + in_proj(xi) + causal conv + silu -> u (bf16), xn (bf16) ----------------
// (unchanged)
__global__ __launch_bounds__(256, 4) void k1_ln_conv(
    const float* __restrict__ input, const float* __restrict__ ln_g, const float* __restrict__ ln_b,
    const float* __restrict__ in_proj_w, const float* __restrict__ conv_w, const float* __restrict__ conv_b,
    bf* __restrict__ u_ws, bf* __restrict__ xn_ws) {
  __shared__ unsigned ldsbuf[8960];               // union: xnT fp32 64x133dw / xiS bf16 256x35dw
  __shared__ float mu_s[64], rs_s[64];
  float* xnT = (float*)ldsbuf;
  unsigned short* xiS = (unsigned short*)ldsbuf;
  int b = blockIdx.x / NT;
  int tile = blockIdx.x - b * NT;
  int l0 = tile * TLV;
  int tid = threadIdx.x;
  const float* inb = input + (size_t)b * CC * LL;
#pragma unroll
  for (int k = 0; k < 32; k++) {
    int i = tid + k * 256;
    int j = i & 63, c = i >> 6;
    int l = l0 - 3 + j;
    xnT[j * XS + c] = (l >= 0 && l < LL) ? inb[c * LL + l] : 0.0f;
  }
  __syncthreads();
  if (tid < 64) {
    float s = 0.f, s2 = 0.f;
    for (int c = 0; c < CC; c++) { float v = xnT[tid * XS + c]; s += v; s2 = fmaf(v, v, s2); }
    float mu = s * (1.0f / CC);
    float var = s2 * (1.0f / CC) - mu * mu;
    mu_s[tid] = mu;
    rs_s[tid] = rsqrtf(var + 1e-5f);
  }
  __syncthreads();
#pragma unroll
  for (int k = 0; k < 32; k++) {
    int i = tid + k * 256;
    int j = i & 63, c = i >> 6;
    xnT[j * XS + c] = (xnT[j * XS + c] - mu_s[j]) * rs_s[j] * ln_g[c] + ln_b[c];
  }
  __syncthreads();
  for (int i = tid; i < CC * TLV; i += 256) {
    int c = i / TLV, j2 = i - c * TLV;
    int l = l0 + j2;
    if (l < LL) xn_ws[((size_t)(b * CC + c)) * LL + l] = f2bf(xnT[(j2 + 3) * XS + c]);
  }
  int g = tid >> 6, j = tid & 63;
  float xr[32];
#pragma unroll
  for (int r = 0; r < 32; r++) xr[r] = xnT[j * XS + g * DM + r];
  bool zero_col = (l0 - 3 + j < 0);
  __syncthreads();
#pragma unroll
  for (int c2 = 0; c2 < 4; c2++) {
    float acc[16];
#pragma unroll
    for (int dd = 0; dd < 16; dd++) {
      const float* w = in_proj_w + (c2 * 16 + dd) * DM;
      float a = 0.f;
#pragma unroll
      for (int r = 0; r < 32; r++) a = fmaf(xr[r], w[r], a);
      acc[dd] = zero_col ? 0.f : a;
    }
    unsigned* xo = (unsigned*)&ldsbuf[(g * 64 + j) * YS + c2 * 8];
#pragma unroll
    for (int k = 0; k < 8; k++)
      xo[k] = pack2(acc[2 * k], acc[2 * k + 1]);
  }
  __syncthreads();
  int d = j;
  float cw0 = conv_w[d * 4 + 0], cw1 = conv_w[d * 4 + 1];
  float cw2 = conv_w[d * 4 + 2], cw3 = conv_w[d * 4 + 3];
  float cb = conv_b[d];
  bf* uo = u_ws + (size_t)(g * BB + b) * LL * DI + d;
  float x3 = 0.f, x2 = 0.f, x1 = 0.f, x0 = 0.f;
  for (int jj = 0; jj < 64; jj++) {
    float xi = us2f(xiS[(g * 64 + jj) * (2 * YS) + d]);
    x3 = x2; x2 = x1; x1 = x0; x0 = xi;
    int l = l0 + jj - 3;
    if (jj >= 3 && l < LL) {
      float pre = x3 * cw0 + x2 * cw1 + x1 * cw2 + x0 * cw3 + cb;
      float uu = pre * sigmoidf_(pre);
      uo[(size_t)l * DI] = f2bf(uu);
    }
  }
}

// ---------------- K23: x_proj -> xdbl  +  FUSED local scan (old k3) ----------------
// Resubmission of round 12 byte-identical: two full audits found no OOB/race/semantic
// bug (uS max 8446/8448, u max 16777215/16777216, hloc max 8388607/8388608, ssum max
// 524287/524288; scan reads only own-wave rows finalized before the barrier; dt bf16 /
// B f16 bit-identical to what k3 consumed). The round-12 "container failed twice" is
// judged infra (precedent: round-5 crash never reproduced a kernel cause; harness
// showed 650 s push stalls this session). If it fails again -> deterministic, revert.
__global__ __launch_bounds__(256) void k2_xproj(
    const bf* __restrict__ u_ws, const float* __restrict__ x_proj_w,
    const float* __restrict__ A_log, const float* __restrict__ dt_proj_w,
    const float* __restrict__ dt_proj_b,
    unsigned* __restrict__ xdbl, __half* __restrict__ hloc, __half* __restrict__ ssum_ws) {
  __shared__ unsigned uS[256 * 33];
  int tid = threadIdx.x;
  size_t pos0 = (size_t)blockIdx.x * 256;
  const unsigned* src = (const unsigned*)u_ws + pos0 * 32;
#pragma unroll
  for (int k = 0; k < 32; k++) {
    int idx = tid + k * 256;
    uS[(idx >> 5) * 33 + (idx & 31)] = src[idx];
  }
  __syncthreads();
  float xdb[34];
#pragma unroll
  for (int e = 0; e < 34; e++) xdb[e] = 0.f;
#pragma unroll
  for (int c2 = 0; c2 < 4; c2++) {
    float f[16];
#pragma unroll
    for (int k = 0; k < 8; k++) {
      unsigned v = uS[tid * 33 + c2 * 8 + k];
      f[2 * k] = blo(v); f[2 * k + 1] = bhi(v);
    }
#pragma unroll
    for (int e = 0; e < 34; e++) {
      const float* w = x_proj_w + e * DI + c2 * 16;
      float a = xdb[e];
#pragma unroll
      for (int i = 0; i < 16; i++) a = fmaf(f[i], w[i], a);
      xdb[e] = a;
    }
  }
  unsigned* row = &uS[tid * 33];
  row[0] = pack2(xdb[0], xdb[1]);
#pragma unroll
  for (int n = 0; n < 8; n++) row[4 + n]  = pack2h(xdb[2 + 2 * n], xdb[3 + 2 * n]);
#pragma unroll
  for (int n = 0; n < 8; n++) row[12 + n] = pack2h(xdb[18 + 2 * n], xdb[19 + 2 * n]);
  __syncthreads();
  unsigned* dst = xdbl + pos0 * XROW;
#pragma unroll
  for (int k = 0; k < XROW; k++) {
    int idx = tid + k * 256;
    int r = idx / XROW, c = idx - r * XROW;
    dst[idx] = uS[r * 33 + c];
  }
  // ---- fused local scan (old k3): wave wv -> local chunks 2wv, 2wv+1 ----
  int wv = tid >> 6, d = tid & 63;
  int s = (int)(pos0 >> 12);                       // sequence
  int ch0 = (int)((pos0 & (LL - 1)) >> 5);         // first chunk (sequence-local)
  float a0 = -__expf(A_log[d * DSN]) * 1.44269504088896f;
  bool ok = ladder_check(A_log, d, a0);
  float w0 = dt_proj_w[2 * d], w1 = dt_proj_w[2 * d + 1], bd = dt_proj_b[d];
  unsigned short* hl = (unsigned short*)hloc;
  for (int cc = 0; cc < 2; cc++) {
    int lch = wv * 2 + cc;                         // 0..7 (wave-uniform)
    int wid = s * NC + ch0 + lch;                  // global chunk id
    hf2 h2[8];
#pragma unroll
    for (int p2 = 0; p2 < 8; p2++) h2[p2] = u2h2(0u);
    float ss = 0.f;
    const unsigned short* up = (const unsigned short*)u_ws
                             + (pos0 + (size_t)lch * CL) * DI + d;
    const unsigned* rowb = &uS[lch * CL * 33];     // this wave's own rows
    if (ok) {
      for (int t = 0; t < CL; t++) {
        const unsigned* r = rowb + t * 33;         // wave-uniform -> broadcast
        unsigned dtp = r[0];
        float x = fmaf(bhi(dtp), w1, fmaf(blo(dtp), w0, bd));
        float delta = softplus_fast(x);
        float uu = us2f(up[(size_t)t * DI]);
        float du = delta * uu;
        ss += delta;
        float E = EXP2F(delta * a0);
        float E2 = E * E;
        hf2 e2; e2.x = (_Float16)E; e2.y = (_Float16)E2;
        hf2 E22; E22.x = (_Float16)E2; E22.y = (_Float16)E2;
        _Float16 duh = (_Float16)du;
        hf2 du2; du2.x = duh; du2.y = duh;
#pragma unroll
        for (int p2 = 0; p2 < 8; p2++) {
          hf2 Bp = u2h2(r[4 + p2]);
          h2[p2] = h2[p2] * e2 + Bp * du2;         // v_pk_mul_f16 + v_pk_fma_f16
          e2 = e2 * E22;                           // v_pk_mul_f16
        }
      }
    } else {
      f2 A2p[8];
#pragma unroll
      for (int p2 = 0; p2 < 8; p2++) {
        A2p[p2].x = -__expf(A_log[d * DSN + 2 * p2]) * 1.44269504088896f;
        A2p[p2].y = -__expf(A_log[d * DSN + 2 * p2 + 1]) * 1.44269504088896f;
      }
      for (int t = 0; t < CL; t++) {
        const unsigned* r = rowb + t * 33;
        unsigned dtp = r[0];
        float x = fmaf(bhi(dtp), w1, fmaf(blo(dtp), w0, bd));
        float delta = softplus_fast(x);
        float uu = us2f(up[(size_t)t * DI]);
        float du = delta * uu;
        ss += delta;
        _Float16 duh = (_Float16)du;
        hf2 du2; du2.x = duh; du2.y = duh;
#pragma unroll
        for (int p2 = 0; p2 < 8; p2++) {
          hf2 ee; ee.x = (_Float16)EXP2F(delta * A2p[p2].x); ee.y = (_Float16)EXP2F(delta * A2p[p2].y);
          hf2 Bp = u2h2(r[4 + p2]);
          h2[p2] = h2[p2] * ee + Bp * du2;
        }
      }
    }
    size_t ob = (size_t)wid * (DSN * DI) + d;
#pragma unroll
    for (int n = 0; n < DSN; n++) {
      _Float16 v = (n & 1) ? h2[n >> 1].y : h2[n >> 1].x;
      hl[ob + n * DI] = *(unsigned short*)&v;      // raw f16 bits
    }
    ssum_ws[wid * DI + d] = __float2half(ss);
  }
}

// ---------------- K4: cross-chunk combine ----------------
// (unchanged from round 11)
__global__ __launch_bounds__(256) void k4_combine(
    const __half* __restrict__ ssum_ws, const float* __restrict__ A_log, __half* hloc_hin) {
  int s = blockIdx.x >> 2;                         // 0..63
  int q = blockIdx.x & 3;                          // n-quarter
  int tid = threadIdx.x;
  int n = q * 4 + (tid >> 6);                      // 0..15
  int d = tid & 63;
  float A2 = -__expf(A_log[d * DSN + n]) * 1.44269504088896f;
  float h = 0.f;
  const __half* sp = ssum_ws + (size_t)s * NC * DI + d;
  __half* hp = hloc_hin + (size_t)s * NC * (DSN * DI) + n * DI + d;
  float hl[4], ssv[4], hln[4], ssn[4];
#pragma unroll
  for (int j = 0; j < 4; j++) {
    hln[j] = __half2float(hp[(size_t)j * (DSN * DI)]);
    ssn[j] = __half2float(sp[j * DI]);
  }
  for (int kb = 0; kb < NC / 4; kb++) {
#pragma unroll
    for (int j = 0; j < 4; j++) { hl[j] = hln[j]; ssv[j] = ssn[j]; }
    if (kb + 1 < NC / 4) {
#pragma unroll
      for (int j = 0; j < 4; j++) {
        int k = (kb + 1) * 4 + j;
        hln[j] = __half2float(hp[(size_t)k * (DSN * DI)]);
        ssn[j] = __half2float(sp[k * DI]);
      }
    }
#pragma unroll
    for (int j = 0; j < 4; j++) {
      int k = kb * 4 + j;
      float ap = EXP2F(A2 * ssv[j]);
      hp[(size_t)k * (DSN * DI)] = __float2half(h);
      h = fmaf(h, ap, hl[j]);
    }
  }
}

// ---------------- K56: scan pass C (y2 -> LDS) + z-gate + out_proj + residual -> output (fp32) ----------------
// (unchanged from round 10/11)
__global__ __launch_bounds__(512, 4) void k56_scan_final(
    const unsigned* __restrict__ xdbl, const bf* __restrict__ u_ws,
    const float* __restrict__ A_log, const float* __restrict__ dt_proj_w,
    const float* __restrict__ dt_proj_b, const float* __restrict__ Dw,
    const __half* __restrict__ hin, const bf* __restrict__ xn_ws,
    const float* __restrict__ in_proj_w, const float* __restrict__ out_proj_w,
    float* __restrict__ out) {
  __shared__ unsigned y2S[4 * 64 * 33];            // 33792 B: per-g 64 rows x 33 dw
  __shared__ __align__(16) unsigned bcS[8 * 512];  // 16384 B: per-wave 32 rows x 16 dw (B,C f16)
  __shared__ unsigned dtS[8 * 32];                 // 1024 B: per-wave 32 rows dt
  int b = blockIdx.x >> 6;
  int cpair = blockIdx.x & 63;                     // 64 col-tiles of 64
  int l0b = cpair * 64;                            // block's first output column
  int tid = threadIdx.x;
  int w = __builtin_amdgcn_readfirstlane(tid >> 6); // 0..7
  int g = w >> 1, half = w & 1;
  int d = tid & 63;
  int chunk = cpair * 2 + half;                    // scalar
  int s_u = __builtin_amdgcn_readfirstlane(g * BB + b);
  float a0 = -__expf(A_log[d * DSN]) * 1.44269504088896f;
  bool ok = ladder_check(A_log, d, a0);
  float w0 = dt_proj_w[2 * d], w1 = dt_proj_w[2 * d + 1], bd = dt_proj_b[d];
  float Dd = Dw[d];
  size_t hb = (size_t)(s_u * NC + chunk) * (DSN * DI) + d;
  const unsigned short* hinus = (const unsigned short*)hin;
  hf2 h2[8];
#pragma unroll
  for (int p2 = 0; p2 < 8; p2++) {
    unsigned lo = hinus[hb + (size_t)(2 * p2) * DI];
    unsigned hi = hinus[hb + (size_t)(2 * p2 + 1) * DI];
    h2[p2] = u2h2(lo | (hi << 16));                // raw f16 bits
  }
  size_t base = (size_t)s_u * LL + (size_t)chunk * CL;
  const unsigned short* up = (const unsigned short*)u_ws + base * DI + d;
  const unsigned* xrow = xdbl + base * XROW;
  // ---- wave-private staging: 32 rows of (dt, B, C) -> LDS (no barrier needed) ----
  int wbc = w * 512, wdt = w * 32;
#pragma unroll
  for (int k = 0; k < 8; k++) {
    int jj2 = k * 64 + d;                          // 0..511
    bcS[wbc + jj2] = xrow[(jj2 >> 4) * XROW + 4 + (jj2 & 15)];
  }
  if (d < 32) dtS[wdt + d] = xrow[d * XROW];
  unsigned short* yout = (unsigned short*)y2S + g * 4224 + (half * CL) * 66 + d;
  if (ok) {
    for (int t = 0; t < CL; t++) {
      unsigned dtp = dtS[wdt + t];
      uint4 bA = *(const uint4*)&bcS[wbc + t * 16];
      uint4 bB = *(const uint4*)&bcS[wbc + t * 16 + 4];
      uint4 cA = *(const uint4*)&bcS[wbc + t * 16 + 8];
      uint4 cB = *(const uint4*)&bcS[wbc + t * 16 + 12];
      float x = fmaf(bhi(dtp), w1, fmaf(blo(dtp), w0, bd));
      float delta = softplus_fast(x);
      float uu = us2f(up[(size_t)t * DI]);
      float du = delta * uu;
      float E = EXP2F(delta * a0);
      float E2 = E * E;
      hf2 e2; e2.x = (_Float16)E; e2.y = (_Float16)E2;
      hf2 E22; E22.x = (_Float16)E2; E22.y = (_Float16)E2;
      _Float16 duh = (_Float16)du;
      hf2 du2; du2.x = duh; du2.y = duh;
      float yacc = 0.f;
      unsigned bw[8] = {bA.x, bA.y, bA.z, bA.w, bB.x, bB.y, bB.z, bB.w};
      unsigned cw[8] = {cA.x, cA.y, cA.z, cA.w, cB.x, cB.y, cB.z, cB.w};
#pragma unroll
      for (int p2 = 0; p2 < 8; p2++) {
        hf2 Bp = u2h2(bw[p2]);
        hf2 Cp = u2h2(cw[p2]);
        h2[p2] = h2[p2] * e2 + Bp * du2;           // pk_mul_f16 + pk_fma_f16
        yacc = FDOT2(h2[p2], Cp, yacc);            // v_dot2_f32_f16
        e2 = e2 * E22;                             // pk_mul_f16
      }
      bf rv = f2bf(yacc + uu * Dd);
      yout[t * 66] = *(unsigned short*)&rv;
    }
  } else {
    f2 A2p[8];
#pragma unroll
    for (int p2 = 0; p2 < 8; p2++) {
      A2p[p2].x = -__expf(A_log[d * DSN + 2 * p2]) * 1.44269504088896f;
      A2p[p2].y = -__expf(A_log[d * DSN + 2 * p2 + 1]) * 1.44269504088896f;
    }
    for (int t = 0; t < CL; t++) {
      unsigned dtp = dtS[wdt + t];
      uint4 bA = *(const uint4*)&bcS[wbc + t * 16];
      uint4 bB = *(const uint4*)&bcS[wbc + t * 16 + 4];
      uint4 cA = *(const uint4*)&bcS[wbc + t * 16 + 8];
      uint4 cB = *(const uint4*)&bcS[wbc + t * 16 + 12];
      float x = fmaf(bhi(dtp), w1, fmaf(blo(dtp), w0, bd));
      float delta = softplus_fast(x);
      float uu = us2f(up[(size_t)t * DI]);
      float du = delta * uu;
      _Float16 duh = (_Float16)du;
      hf2 du2; du2.x = duh; du2.y = duh;
      float yacc = 0.f;
      unsigned bw[8] = {bA.x, bA.y, bA.z, bA.w, bB.x, bB.y, bB.z, bB.w};
      unsigned cw[8] = {cA.x, cA.y, cA.z, cA.w, cB.x, cB.y, cB.z, cB.w};
#pragma unroll
      for (int p2 = 0; p2 < 8; p2++) {
        hf2 ee; ee.x = (_Float16)EXP2F(delta * A2p[p2].x); ee.y = (_Float16)EXP2F(delta * A2p[p2].y);
        hf2 Bp = u2h2(bw[p2]);
        hf2 Cp = u2h2(cw[p2]);
        h2[p2] = h2[p2] * ee + Bp * du2;
        yacc = FDOT2(h2[p2], Cp, yacc);
      }
      bf rv = f2bf(yacc + uu * Dd);
      yout[t * 66] = *(unsigned short*)&rv;
    }
  }
  __syncthreads();
  // ---- z projection (after barrier; acc never lives across the scan) ----
  int p = half;
  int j = d;
  const unsigned short* xnp = (const unsigned short*)xn_ws
                            + ((size_t)(b * CC + g * DM)) * LL + l0b + j;
  float acc[32];                                   // this wave's dd = p*32 .. p*32+31
#pragma unroll
  for (int dd = 0; dd < 32; dd++) acc[dd] = 0.f;
#pragma unroll
  for (int c4 = 0; c4 < 4; c4++) {
    float xc[8];
#pragma unroll
    for (int r8 = 0; r8 < 8; r8++)
      xc[r8] = us2f(xnp[(size_t)(c4 * 8 + r8) * LL]);   // lanes j consecutive -> coalesced
#pragma unroll
    for (int dd = 0; dd < 32; dd++) {              // weights wave-uniform -> s_load
      const float* wz = in_proj_w + (DI + p * 32 + dd) * DM + c4 * 8;
      float a = acc[dd];
#pragma unroll
      for (int r8 = 0; r8 < 8; r8++) a = fmaf(xc[r8], wz[r8], a);
      acc[dd] = a;
    }
  }
  // ---- gate: y3 = y2 * silu(z); own (g,j) row, this wave's dword cols p*16..p*16+15 ----
  const unsigned* yrow = y2S + g * 2112 + j * 33;  // banks (j+k)%32 -> conflict-free
#pragma unroll
  for (int kk = 0; kk < 16; kk++) {
    unsigned v = yrow[p * 16 + kk];
    float z0 = acc[2 * kk], z1 = acc[2 * kk + 1];
    acc[2 * kk]     = blo(v) * (z0 * sigmoidf_(z0));
    acc[2 * kk + 1] = bhi(v) * (z1 * sigmoidf_(z1));
  }
  __syncthreads();                                 // y2S fully consumed -> reuse as partials
  // ---- phase A: partials for the OTHER wave's jj half (both waves work) ----
  float* prow = (float*)y2S + g * 2112 + j * 33;   // stride-33 -> conflict-free
  int jjb = (1 - p) * 16;
#pragma unroll
  for (int jj = 0; jj < 16; jj++) {
    const float* wo = out_proj_w + (jjb + jj) * DI + p * 32;
    float a = 0.f;
#pragma unroll
    for (int dd = 0; dd < 32; dd++) a = fmaf(acc[dd], wo[dd], a);
    prow[jjb + jj] = a;
  }
  __syncthreads();
  // ---- phase B: finalize own half (partial + own dot + residual), store 16 rows/wave ----
  int jf = p * 16;
  float* ob = out + ((size_t)(b * CC + g * DM)) * LL + l0b + j;
#pragma unroll
  for (int jj = 0; jj < 16; jj++) {
    const float* wo = out_proj_w + (jf + jj) * DI + p * 32;
    float a = us2f(xnp[(size_t)(jf + jj) * LL]) + prow[jf + jj];
#pragma unroll
    for (int dd = 0; dd < 32; dd++) a = fmaf(acc[dd], wo[dd], a);
    ob[(size_t)(jf + jj) * LL] = a;                // coalesced 256B
  }
}

extern "C" void kernel_launch(void* const* d_in, const int* in_sizes, int n_in,
                              void* d_out, int out_size, void* d_ws, size_t ws_size,
                              hipStream_t stream) {
  const float* input     = (const float*)d_in[0];
  const float* ln_g      = (const float*)d_in[1];
  const float* ln_b      = (const float*)d_in[2];
  const float* in_proj_w = (const float*)d_in[3];
  const float* conv_w    = (const float*)d_in[4];
  const float* conv_b    = (const float*)d_in[5];
  const float* x_proj_w  = (const float*)d_in[6];
  const float* dt_proj_w = (const float*)d_in[7];
  const float* dt_proj_b = (const float*)d_in[8];
  const float* A_log     = (const float*)d_in[9];
  const float* Dw        = (const float*)d_in[10];
  const float* out_proj_w= (const float*)d_in[11];
  float* out = (float*)d_out;

  char* ws = (char*)d_ws;
  bf*       u_ws  = (bf*)(ws);                    // 32 MiB
  unsigned* xdbl  = (unsigned*)(ws + 33554432);   // 20 MiB
  bf*       xn_ws = (bf*)(ws + 54525952);         // 16 MiB
  __half*   hloc  = (__half*)(ws + 71303168);     // 16 MiB fp16 (NC=128; hin aliases after k4)
  __half*   ssum  = (__half*)(ws + 88080384);     // 1 MiB fp16 (total 89,128,960 B — known-good)
  (void)in_sizes; (void)n_in; (void)out_size; (void)ws_size;

  hipLaunchKernelGGL(k1_ln_conv, dim3(BB * NT), dim3(256), 0, stream,
                     input, ln_g, ln_b, in_proj_w, conv_w, conv_b, u_ws, xn_ws);
  hipLaunchKernelGGL(k2_xproj, dim3(1024), dim3(256), 0, stream,
                     u_ws, x_proj_w, A_log, dt_proj_w, dt_proj_b, xdbl, hloc, ssum);
  hipLaunchKernelGGL(k4_combine, dim3(GG * 4), dim3(256), 0, stream,
                     ssum, A_log, hloc);
  hipLaunchKernelGGL(k56_scan_final, dim3(BB * NC / 2), dim3(512), 0, stream,
                     xdbl, u_ws, A_log, dt_proj_w, dt_proj_b, Dw, hloc, xn_ws,
                     in_proj_w, out_proj_w, out);
}